// Round 6
// baseline (359.169 us; speedup 1.0000x reference)
//
#include <hip/hip_runtime.h>
#include <hip/hip_bf16.h>
#include <math.h>

// Problem constants
#define BB 4
#define SS 2048
#define DD 256
#define HH 8
#define HSZ 32

typedef __attribute__((ext_vector_type(8))) short short8;   // 8 bf16 (4 VGPRs)
typedef __attribute__((ext_vector_type(4))) float f32x4;    // MFMA C/D frag

__device__ __forceinline__ float gelu_f(float x) {
    float x3 = x * x * x;
    float z = 0.7978845608028654f * fmaf(0.044715f, x3, x);
    float e = __expf(2.0f * z);
    float t = 1.0f - 2.0f / (e + 1.0f);
    return 0.5f * x * (1.0f + t);
}

__device__ __forceinline__ unsigned short f2bf(float f) {
    unsigned int u = __float_as_uint(f);
    u = (u + 0x7fffu + ((u >> 16) & 1u)) >> 16;
    return (unsigned short)u;
}

// pack two fp32 -> two bf16 (truncation; bias cancels in softmax p/sum(p))
__device__ __forceinline__ unsigned int pack_bf16_tr(float a, float b) {
    return (__float_as_uint(a) >> 16) | (__float_as_uint(b) & 0xffff0000u);
}

// ---------------- Weight prep: transpose [R][256] fp32 -> [256][R] bf16 ----------------
__global__ __launch_bounds__(256) void wprep_kernel(
    const float* __restrict__ src, unsigned short* __restrict__ dst, int R)
{
    __shared__ unsigned short t[32][33];
    const int tx = threadIdx.x & 31, ty = threadIdx.x >> 5;
    const int tiles_c = 256 / 32;
    const int r0 = (blockIdx.x / tiles_c) * 32, c0 = (blockIdx.x % tiles_c) * 32;
    #pragma unroll
    for (int j = 0; j < 32; j += 8)
        t[ty + j][tx] = f2bf(src[(r0 + ty + j) * 256 + c0 + tx]);
    __syncthreads();
    #pragma unroll
    for (int j = 0; j < 32; j += 8)
        dst[(c0 + ty + j) * R + r0 + tx] = t[tx][ty + j];
}

// ---------------- V transpose: v_bf [B*S][256] -> Vt [B*H*32 d][S] ----------------
__global__ __launch_bounds__(256) void vtrans_kernel(
    const unsigned short* __restrict__ v_bf, unsigned short* __restrict__ Vt, int S)
{
    __shared__ unsigned short t[32][34];
    const int stiles = S / 32;
    const int bh = blockIdx.x / stiles;
    const int s0 = (blockIdx.x % stiles) * 32;
    const int b = bh / HH, h = bh % HH;
    const int d = threadIdx.x & 31, sl = threadIdx.x >> 5;
    #pragma unroll
    for (int j = 0; j < 32; j += 8)
        t[sl + j][d] = v_bf[(size_t)(b * S + s0 + sl + j) * 256 + h * 32 + d];
    __syncthreads();
    const int sw = threadIdx.x & 31, dw = threadIdx.x >> 5;
    #pragma unroll
    for (int j = 0; j < 32; j += 8)
        Vt[(size_t)(bh * 32 + dw + j) * S + s0 + sw] = t[sw][dw + j];
}

// ---------------- LayerNorm, bf16 out (optionally fused residual add) ----------------
template<bool HASRES>
__global__ __launch_bounds__(256) void ln_kernel(
    const float* __restrict__ x, const float* __restrict__ addin,
    const float* __restrict__ g, const float* __restrict__ bvec,
    float* __restrict__ resid_out, unsigned short* __restrict__ oln_bf)
{
    int t = blockIdx.x, i = threadIdx.x;
    int idx = t * DD + i;
    float v = x[idx];
    if (HASRES) {
        v += addin[idx];
        resid_out[idx] = v;
    }
    __shared__ float red[256];
    red[i] = v;
    __syncthreads();
    for (int st = 128; st > 0; st >>= 1) {
        if (i < st) red[i] += red[i + st];
        __syncthreads();
    }
    float mean = red[0] * (1.0f / 256.0f);
    __syncthreads();
    float dv = v - mean;
    red[i] = dv * dv;
    __syncthreads();
    for (int st = 128; st > 0; st >>= 1) {
        if (i < st) red[i] += red[i + st];
        __syncthreads();
    }
    float var = red[0] * (1.0f / 256.0f);
    float r = rsqrtf(var + 1e-6f);
    oln_bf[idx] = f2bf(dv * r * g[i] + bvec[i]);
}

// ---------------- Conv1d as bf16 MFMA implicit GEMM, 32-token tiles ----------------
template<int KS, bool GELU_OUT, int NSETS, int OUTMODE>
__global__ __launch_bounds__(256) void convf_kernel(
    const unsigned short* __restrict__ in0, const unsigned short* __restrict__ in1,
    const unsigned short* __restrict__ in2,
    const unsigned short* __restrict__ W0, const unsigned short* __restrict__ W1,
    const unsigned short* __restrict__ W2,
    const float* __restrict__ bias0, const float* __restrict__ bias1,
    const float* __restrict__ bias2,
    unsigned short* __restrict__ ob0, unsigned short* __restrict__ ob1,
    unsigned short* __restrict__ ob2,
    const float* __restrict__ res, float* __restrict__ outf, int S)
{
    constexpr int TSM = 32;
    constexpr int R = TSM + KS - 1;
    constexpr int pad = (KS - 1) / 2;
    constexpr int KD = KS * 256;
    constexpr int LDW = 264;
    __shared__ __align__(16) unsigned short in_lds[R][LDW];

    int set, tile;
    if (NSETS == 3) { set = blockIdx.x % 3; tile = blockIdx.x / 3; }
    else           { set = 0;              tile = blockIdx.x; }
    const unsigned short* in   = set == 0 ? in0 : (set == 1 ? in1 : in2);
    const unsigned short* Wt   = set == 0 ? W0  : (set == 1 ? W1  : W2);
    const float* bias          = set == 0 ? bias0 : (set == 1 ? bias1 : bias2);
    unsigned short* outb       = set == 0 ? ob0 : (set == 1 ? ob1 : ob2);

    const int tid = threadIdx.x;
    const int lane = tid & 63, wv = tid >> 6;
    const int lm = lane & 15, lq = lane >> 4;
    const int tpb = S / TSM;
    const int b = tile / tpb;
    const int s0 = (tile % tpb) * TSM;

    for (int i = tid; i < R * 32; i += 256) {
        int r = i >> 5, c8 = (i & 31) << 3;
        int s = s0 + r - pad;
        int4 val = make_int4(0, 0, 0, 0);
        if (s >= 0 && s < S)
            val = *(const int4*)&in[(size_t)(b * S + s) * 256 + c8];
        *(int4*)&in_lds[r][c8] = val;
    }

    f32x4 acc[2][4];
    #pragma unroll
    for (int mt = 0; mt < 2; ++mt)
        #pragma unroll
        for (int nt = 0; nt < 4; ++nt) acc[mt][nt] = (f32x4){0.f, 0.f, 0.f, 0.f};

    const int n0 = wv * 64;
    __syncthreads();
    #pragma unroll
    for (int kk = 0; kk < KS; ++kk) {
        #pragma unroll 2
        for (int ic = 0; ic < 256; ic += 32) {
            short8 a0 = *(const short8*)&in_lds[kk + lm][ic + lq * 8];
            short8 a1 = *(const short8*)&in_lds[kk + 16 + lm][ic + lq * 8];
            int kcol = kk * 256 + ic + lq * 8;
            #pragma unroll
            for (int nt = 0; nt < 4; ++nt) {
                short8 bfr = *(const short8*)&Wt[(size_t)(n0 + nt * 16 + lm) * KD + kcol];
                acc[0][nt] = __builtin_amdgcn_mfma_f32_16x16x32_bf16(a0, bfr, acc[0][nt], 0, 0, 0);
                acc[1][nt] = __builtin_amdgcn_mfma_f32_16x16x32_bf16(a1, bfr, acc[1][nt], 0, 0, 0);
            }
        }
    }

    #pragma unroll
    for (int mt = 0; mt < 2; ++mt) {
        #pragma unroll
        for (int nt = 0; nt < 4; ++nt) {
            int o = n0 + nt * 16 + lm;
            float bv = bias[o];
            #pragma unroll
            for (int r = 0; r < 4; ++r) {
                int t = s0 + mt * 16 + lq * 4 + r;
                float val = acc[mt][nt][r] + bv;
                if (GELU_OUT) val = gelu_f(val);
                size_t idx = (size_t)(b * S + t) * 256 + o;
                if (OUTMODE == 0) outb[idx] = f2bf(val);
                else outf[idx] = val + res[idx];
            }
        }
    }
}

// ---------------- MFMA flash attention v3 ----------------
// K-frags, Vt-frags, mask: direct from global (VMEM pipe; L1/L2-resident).
// Scores computed TRANSPOSED (A=K, B=Q) so each lane holds 4 consecutive keys
// of one query row -> P to LDS as 2x ds_write_b64, back as 1x ds_read_b128.
// p_lds is wave-private: NO barriers. Fixed-shift softmax (exact), exp2-based.
__global__ __launch_bounds__(256) void attn_mfma_kernel(
    const unsigned short* __restrict__ Qb, const unsigned short* __restrict__ Kb,
    const unsigned short* __restrict__ Vt, const int* __restrict__ mask,
    float* __restrict__ Out, int S, int H)
{
    constexpr int LDP = 40;  // P row stride (elems): 80 B rows; 2-way aliasing only
    __shared__ __align__(16) unsigned short p_lds[4][16 * LDP];

    const int qtiles = S / 64;
    const int qt = (blockIdx.x % qtiles) * 64;
    const int bh = blockIdx.x / qtiles;
    const int b = bh / H, h = bh % H;
    const int tid = threadIdx.x;
    const int lane = tid & 63, wv = tid >> 6;
    const int lm = lane & 15, lq = lane >> 4;
    const int q0 = qt + wv * 16;

    // B-frag: Q[n=q0+lm][k=d=lq*8+j]
    short8 qfrag = *(const short8*)&Qb[(size_t)(b * S + q0 + lm) * 256 + h * 32 + lq * 8];

    short8 ones;
    #pragma unroll
    for (int j = 0; j < 8; ++j) ones[j] = (short)0x3F80;  // bf16 1.0

    f32x4 o0 = {0.f, 0.f, 0.f, 0.f}, o1 = {0.f, 0.f, 0.f, 0.f};
    const f32x4 zf = {0.f, 0.f, 0.f, 0.f};
    float l[4] = {0.f, 0.f, 0.f, 0.f};

    // exp(z*scale + madd) == exp2(z*scale2 + madd2)
    const float scale2 = 0.17677669529663687f * 1.4426950408889634f;
    const float M_ON  = -8.0f * 1.4426950408889634f;   // unmasked shift
    const float M_OFF = -1.442695e30f;                 // masked -> exp2 -> 0

    // global frag pointers (lane-fixed offsets, advance by 32 keys per chunk)
    const unsigned short* kp0 = Kb + (size_t)(b * S + lm) * 256 + h * 32 + lq * 8;
    const unsigned short* kp1 = kp0 + 16 * 256;
    const unsigned short* vp0 = Vt + (size_t)(bh * 32 + lm) * S + lq * 8;
    const unsigned short* vp1 = vp0 + (size_t)16 * S;
    const int* mp0 = mask + b * S + lq * 4;
    const int* mp1 = mp0 + 16;

    unsigned short* pw = p_lds[wv];
    const int pst = lm * LDP + lq * 4;       // store base (elems)
    const int prd = lm * LDP + lq * 8;       // read base

    for (int c = 0; c < S / 32; ++c) {
        // scores transposed: D[m=key][n=query]
        short8 kf0 = *(const short8*)(kp0 + (size_t)c * 32 * 256);
        short8 kf1 = *(const short8*)(kp1 + (size_t)c * 32 * 256);
        f32x4 s0 = __builtin_amdgcn_mfma_f32_16x16x32_bf16(kf0, qfrag, zf, 0, 0, 0);
        f32x4 s1 = __builtin_amdgcn_mfma_f32_16x16x32_bf16(kf1, qfrag, zf, 0, 0, 0);

        int4 ml0 = *(const int4*)(mp0 + c * 32);
        int4 ml1 = *(const int4*)(mp1 + c * 32);

        float p[8];
        p[0] = exp2f(fmaf(s0[0], scale2, ml0.x ? M_ON : M_OFF));
        p[1] = exp2f(fmaf(s0[1], scale2, ml0.y ? M_ON : M_OFF));
        p[2] = exp2f(fmaf(s0[2], scale2, ml0.z ? M_ON : M_OFF));
        p[3] = exp2f(fmaf(s0[3], scale2, ml0.w ? M_ON : M_OFF));
        p[4] = exp2f(fmaf(s1[0], scale2, ml1.x ? M_ON : M_OFF));
        p[5] = exp2f(fmaf(s1[1], scale2, ml1.y ? M_ON : M_OFF));
        p[6] = exp2f(fmaf(s1[2], scale2, ml1.z ? M_ON : M_OFF));
        p[7] = exp2f(fmaf(s1[3], scale2, ml1.w ? M_ON : M_OFF));

        // store P[query=lm][keys 4lq..+3 and 16+4lq..+3] as packed bf16 b64s
        uint2 w0, w1;
        w0.x = pack_bf16_tr(p[0], p[1]); w0.y = pack_bf16_tr(p[2], p[3]);
        w1.x = pack_bf16_tr(p[4], p[5]); w1.y = pack_bf16_tr(p[6], p[7]);
        *(uint2*)&pw[pst] = w0;
        *(uint2*)&pw[pst + 16] = w1;

        // read back as A-frag: A[m=query=lm][k=key=lq*8+j] (wave-private)
        short8 pA = *(const short8*)&pw[prd];

        short8 bv0 = *(const short8*)(vp0 + c * 32);
        short8 bv1 = *(const short8*)(vp1 + c * 32);
        f32x4 lf = __builtin_amdgcn_mfma_f32_16x16x32_bf16(pA, ones, zf, 0, 0, 0);
        o0 = __builtin_amdgcn_mfma_f32_16x16x32_bf16(pA, bv0, o0, 0, 0, 0);
        o1 = __builtin_amdgcn_mfma_f32_16x16x32_bf16(pA, bv1, o1, 0, 0, 0);
        #pragma unroll
        for (int r = 0; r < 4; ++r) l[r] += lf[r];
    }

    #pragma unroll
    for (int r = 0; r < 4; ++r) {
        float inv = 1.0f / l[r];
        size_t base = (size_t)(b * S + q0 + lq * 4 + r) * 256 + h * 32;
        Out[base + lm] = o0[r] * inv;
        Out[base + 16 + lm] = o1[r] * inv;
    }
}

extern "C" void kernel_launch(void* const* d_in, const int* in_sizes, int n_in,
                              void* d_out, int out_size, void* d_ws, size_t ws_size,
                              hipStream_t stream) {
    (void)in_sizes; (void)n_in; (void)out_size; (void)ws_size;
    const float* x    = (const float*)d_in[0];
    const float* ln1g = (const float*)d_in[1];
    const float* ln1b = (const float*)d_in[2];
    const float* Wq   = (const float*)d_in[3];
    const float* bq   = (const float*)d_in[4];
    const float* Wk   = (const float*)d_in[5];
    const float* bk   = (const float*)d_in[6];
    const float* Wv   = (const float*)d_in[7];
    const float* bv   = (const float*)d_in[8];
    const float* ln2g = (const float*)d_in[9];
    const float* ln2b = (const float*)d_in[10];
    const float* Wo1  = (const float*)d_in[11];
    const float* bo1  = (const float*)d_in[12];
    const float* Wo2  = (const float*)d_in[13];
    const float* bo2  = (const float*)d_in[14];
    const int*   mask = (const int*)d_in[15];
    float* out = (float*)d_out;

    const int S = SS, H = HH;
    const int T = BB * SS;                 // 8192 tokens
    const size_t NE = (size_t)T * DD;      // 2M elements
    float* ws    = (float*)d_ws;
    float* attn  = ws + 0 * NE;            // fp32 attn out; holds tk/tv (bf16) earlier
    float* resid = ws + 1 * NE;
    unsigned short* q_bf   = (unsigned short*)(ws + 2 * NE);
    unsigned short* k_bf   = q_bf + NE;
    unsigned short* v_bf   = k_bf + NE;
    unsigned short* h_bf   = v_bf + NE;
    unsigned short* tq_bf  = h_bf + NE;    // layer-1 q out; later MLP tmp
    unsigned short* wt     = tq_bf + NE;
    unsigned short* tk_bf  = (unsigned short*)attn;       // dead before attn writes
    unsigned short* tv_bf  = tk_bf + NE;
    const int WC = 3 * DD * DD;            // 196608
    const int WM = DD * DD;
    unsigned short* wtq0 = wt;
    unsigned short* wtq1 = wt + WC;
    unsigned short* wtk0 = wt + 2 * WC;
    unsigned short* wtk1 = wt + 3 * WC;
    unsigned short* wtv0 = wt + 4 * WC;
    unsigned short* wtv1 = wt + 5 * WC;
    unsigned short* wto1 = wt + 6 * WC;
    unsigned short* wto2 = wt + 6 * WC + WM;
    unsigned short* vt_g = wt + 6 * WC + 2 * WM;  // transposed V [B*H*32][S]

    const int GC = (768 / 32) * (256 / 32);
    const int GM = (256 / 32) * (256 / 32);
    wprep_kernel<<<GC, 256, 0, stream>>>(Wq,      wtq0, 768);
    wprep_kernel<<<GC, 256, 0, stream>>>(Wq + WC, wtq1, 768);
    wprep_kernel<<<GC, 256, 0, stream>>>(Wk,      wtk0, 768);
    wprep_kernel<<<GC, 256, 0, stream>>>(Wk + WC, wtk1, 768);
    wprep_kernel<<<GC, 256, 0, stream>>>(Wv,      wtv0, 768);
    wprep_kernel<<<GC, 256, 0, stream>>>(Wv + WC, wtv1, 768);
    wprep_kernel<<<GM, 256, 0, stream>>>(Wo1,     wto1, 256);
    wprep_kernel<<<GM, 256, 0, stream>>>(Wo2,     wto2, 256);

    // LN1 -> bf16
    ln_kernel<false><<<T, 256, 0, stream>>>(x, nullptr, ln1g, ln1b, nullptr, h_bf);

    const int CG1 = (T / 32) * 3;
    const int CG  = T / 32;

    // temporal encoders, fused across q/k/v
    convf_kernel<3, true, 3, 0><<<CG1, 256, 0, stream>>>(
        h_bf, h_bf, h_bf, wtq0, wtk0, wtv0, bq, bk, bv,
        tq_bf, tk_bf, tv_bf, nullptr, nullptr, S);
    convf_kernel<3, false, 3, 0><<<CG1, 256, 0, stream>>>(
        tq_bf, tk_bf, tv_bf, wtq1, wtk1, wtv1, bq + DD, bk + DD, bv + DD,
        q_bf, k_bf, v_bf, nullptr, nullptr, S);

    // V transpose for attention B-frags
    vtrans_kernel<<<BB * H * (S / 32), 256, 0, stream>>>(v_bf, vt_g, S);

    // MFMA attention -> attn (fp32)
    attn_mfma_kernel<<<BB * H * (S / 64), 256, 0, stream>>>(q_bf, k_bf, vt_g, mask, attn, S, H);

    // residual + LN2
    ln_kernel<true><<<T, 256, 0, stream>>>(x, attn, ln2g, ln2b, resid, h_bf);

    // output MLP
    convf_kernel<1, true, 1, 0><<<CG, 256, 0, stream>>>(
        h_bf, nullptr, nullptr, wto1, nullptr, nullptr, bo1, nullptr, nullptr,
        tq_bf, nullptr, nullptr, nullptr, nullptr, S);
    convf_kernel<1, false, 1, 2><<<CG, 256, 0, stream>>>(
        tq_bf, nullptr, nullptr, wto2, nullptr, nullptr, bo2, nullptr, nullptr,
        nullptr, nullptr, nullptr, resid, out, S);
}

// Round 7
// 297.077 us; speedup vs baseline: 1.2090x; 1.2090x over previous
//
#include <hip/hip_runtime.h>
#include <hip/hip_bf16.h>
#include <math.h>

// Problem constants
#define BB 4
#define SS 2048
#define DD 256
#define HH 8
#define HSZ 32

typedef __attribute__((ext_vector_type(8))) short short8;   // 8 bf16 (4 VGPRs)
typedef __attribute__((ext_vector_type(4))) float f32x4;    // MFMA C/D frag

__device__ __forceinline__ float gelu_f(float x) {
    float x3 = x * x * x;
    float z = 0.7978845608028654f * fmaf(0.044715f, x3, x);
    float e = __expf(2.0f * z);
    float t = 1.0f - 2.0f / (e + 1.0f);
    return 0.5f * x * (1.0f + t);
}

__device__ __forceinline__ unsigned short f2bf(float f) {
    unsigned int u = __float_as_uint(f);
    u = (u + 0x7fffu + ((u >> 16) & 1u)) >> 16;
    return (unsigned short)u;
}

// pack two fp32 -> two bf16 (truncation; bias cancels in softmax p/sum(p))
__device__ __forceinline__ unsigned int pack_bf16_tr(float a, float b) {
    return (__float_as_uint(a) >> 16) | (__float_as_uint(b) & 0xffff0000u);
}

// ---------------- Weight prep: transpose [R][256] fp32 -> [256][R] bf16 ----------------
__global__ __launch_bounds__(256) void wprep_kernel(
    const float* __restrict__ src, unsigned short* __restrict__ dst, int R)
{
    __shared__ unsigned short t[32][33];
    const int tx = threadIdx.x & 31, ty = threadIdx.x >> 5;
    const int tiles_c = 256 / 32;
    const int r0 = (blockIdx.x / tiles_c) * 32, c0 = (blockIdx.x % tiles_c) * 32;
    #pragma unroll
    for (int j = 0; j < 32; j += 8)
        t[ty + j][tx] = f2bf(src[(r0 + ty + j) * 256 + c0 + tx]);
    __syncthreads();
    #pragma unroll
    for (int j = 0; j < 32; j += 8)
        dst[(c0 + ty + j) * R + r0 + tx] = t[tx][ty + j];
}

// ---------------- V transpose: v_bf [B*S][256] -> Vt [B*H*32 d][S] ----------------
__global__ __launch_bounds__(256) void vtrans_kernel(
    const unsigned short* __restrict__ v_bf, unsigned short* __restrict__ Vt, int S)
{
    __shared__ unsigned short t[32][34];
    const int stiles = S / 32;
    const int bh = blockIdx.x / stiles;
    const int s0 = (blockIdx.x % stiles) * 32;
    const int b = bh / HH, h = bh % HH;
    const int d = threadIdx.x & 31, sl = threadIdx.x >> 5;
    #pragma unroll
    for (int j = 0; j < 32; j += 8)
        t[sl + j][d] = v_bf[(size_t)(b * S + s0 + sl + j) * 256 + h * 32 + d];
    __syncthreads();
    const int sw = threadIdx.x & 31, dw = threadIdx.x >> 5;
    #pragma unroll
    for (int j = 0; j < 32; j += 8)
        Vt[(size_t)(bh * 32 + dw + j) * S + s0 + sw] = t[sw][dw + j];
}

// ---------------- LayerNorm, bf16 out (optionally fused residual add) ----------------
template<bool HASRES>
__global__ __launch_bounds__(256) void ln_kernel(
    const float* __restrict__ x, const float* __restrict__ addin,
    const float* __restrict__ g, const float* __restrict__ bvec,
    float* __restrict__ resid_out, unsigned short* __restrict__ oln_bf)
{
    int t = blockIdx.x, i = threadIdx.x;
    int idx = t * DD + i;
    float v = x[idx];
    if (HASRES) {
        v += addin[idx];
        resid_out[idx] = v;
    }
    __shared__ float red[256];
    red[i] = v;
    __syncthreads();
    for (int st = 128; st > 0; st >>= 1) {
        if (i < st) red[i] += red[i + st];
        __syncthreads();
    }
    float mean = red[0] * (1.0f / 256.0f);
    __syncthreads();
    float dv = v - mean;
    red[i] = dv * dv;
    __syncthreads();
    for (int st = 128; st > 0; st >>= 1) {
        if (i < st) red[i] += red[i + st];
        __syncthreads();
    }
    float var = red[0] * (1.0f / 256.0f);
    float r = rsqrtf(var + 1e-6f);
    oln_bf[idx] = f2bf(dv * r * g[i] + bvec[i]);
}

// ---------------- Conv1d as bf16 MFMA implicit GEMM, 32-token tiles ----------------
template<int KS, bool GELU_OUT, int NSETS, int OUTMODE>
__global__ __launch_bounds__(256) void convf_kernel(
    const unsigned short* __restrict__ in0, const unsigned short* __restrict__ in1,
    const unsigned short* __restrict__ in2,
    const unsigned short* __restrict__ W0, const unsigned short* __restrict__ W1,
    const unsigned short* __restrict__ W2,
    const float* __restrict__ bias0, const float* __restrict__ bias1,
    const float* __restrict__ bias2,
    unsigned short* __restrict__ ob0, unsigned short* __restrict__ ob1,
    unsigned short* __restrict__ ob2,
    const float* __restrict__ res, float* __restrict__ outf, int S)
{
    constexpr int TSM = 32;
    constexpr int R = TSM + KS - 1;
    constexpr int pad = (KS - 1) / 2;
    constexpr int KD = KS * 256;
    constexpr int LDW = 264;
    __shared__ __align__(16) unsigned short in_lds[R][LDW];

    int set, tile;
    if (NSETS == 3) { set = blockIdx.x % 3; tile = blockIdx.x / 3; }
    else           { set = 0;              tile = blockIdx.x; }
    const unsigned short* in   = set == 0 ? in0 : (set == 1 ? in1 : in2);
    const unsigned short* Wt   = set == 0 ? W0  : (set == 1 ? W1  : W2);
    const float* bias          = set == 0 ? bias0 : (set == 1 ? bias1 : bias2);
    unsigned short* outb       = set == 0 ? ob0 : (set == 1 ? ob1 : ob2);

    const int tid = threadIdx.x;
    const int lane = tid & 63, wv = tid >> 6;
    const int lm = lane & 15, lq = lane >> 4;
    const int tpb = S / TSM;
    const int b = tile / tpb;
    const int s0 = (tile % tpb) * TSM;

    for (int i = tid; i < R * 32; i += 256) {
        int r = i >> 5, c8 = (i & 31) << 3;
        int s = s0 + r - pad;
        int4 val = make_int4(0, 0, 0, 0);
        if (s >= 0 && s < S)
            val = *(const int4*)&in[(size_t)(b * S + s) * 256 + c8];
        *(int4*)&in_lds[r][c8] = val;
    }

    f32x4 acc[2][4];
    #pragma unroll
    for (int mt = 0; mt < 2; ++mt)
        #pragma unroll
        for (int nt = 0; nt < 4; ++nt) acc[mt][nt] = (f32x4){0.f, 0.f, 0.f, 0.f};

    const int n0 = wv * 64;
    __syncthreads();
    #pragma unroll
    for (int kk = 0; kk < KS; ++kk) {
        #pragma unroll 2
        for (int ic = 0; ic < 256; ic += 32) {
            short8 a0 = *(const short8*)&in_lds[kk + lm][ic + lq * 8];
            short8 a1 = *(const short8*)&in_lds[kk + 16 + lm][ic + lq * 8];
            int kcol = kk * 256 + ic + lq * 8;
            #pragma unroll
            for (int nt = 0; nt < 4; ++nt) {
                short8 bfr = *(const short8*)&Wt[(size_t)(n0 + nt * 16 + lm) * KD + kcol];
                acc[0][nt] = __builtin_amdgcn_mfma_f32_16x16x32_bf16(a0, bfr, acc[0][nt], 0, 0, 0);
                acc[1][nt] = __builtin_amdgcn_mfma_f32_16x16x32_bf16(a1, bfr, acc[1][nt], 0, 0, 0);
            }
        }
    }

    #pragma unroll
    for (int mt = 0; mt < 2; ++mt) {
        #pragma unroll
        for (int nt = 0; nt < 4; ++nt) {
            int o = n0 + nt * 16 + lm;
            float bv = bias[o];
            #pragma unroll
            for (int r = 0; r < 4; ++r) {
                int t = s0 + mt * 16 + lq * 4 + r;
                float val = acc[mt][nt][r] + bv;
                if (GELU_OUT) val = gelu_f(val);
                size_t idx = (size_t)(b * S + t) * 256 + o;
                if (OUTMODE == 0) outb[idx] = f2bf(val);
                else outf[idx] = val + res[idx];
            }
        }
    }
}

// ---------------- MFMA flash attention v4 ----------------
// K and Vt cooperatively staged in LDS (double-buffered, ONE barrier/chunk,
// next chunk's global loads issued before current chunk's compute).
// Transposed-score MFMA (A=K,B=Q) -> packed P roundtrip: 2x ds_write_b64 +
// 1x ds_read_b128. Mask via global int4. Fixed-shift exp2 softmax (exact).
__global__ __launch_bounds__(256) void attn_mfma_kernel(
    const unsigned short* __restrict__ Qb, const unsigned short* __restrict__ Kb,
    const unsigned short* __restrict__ Vt, const int* __restrict__ mask,
    float* __restrict__ Out, int S, int H)
{
    constexpr int LDK = 40;  // staged K / vT row stride (elems)
    constexpr int LDP = 40;  // P row stride
    __shared__ __align__(16) unsigned short k_lds[2][32 * LDK];
    __shared__ __align__(16) unsigned short v_lds[2][32 * LDK];
    __shared__ __align__(16) unsigned short p_lds[4][16 * LDP];

    const int qtiles = S / 64;
    const int qt = (blockIdx.x % qtiles) * 64;
    const int bh = blockIdx.x / qtiles;
    const int b = bh / H, h = bh % H;
    const int tid = threadIdx.x;
    const int lane = tid & 63, wv = tid >> 6;
    const int lm = lane & 15, lq = lane >> 4;
    const int q0 = qt + wv * 16;

    // B-frag for transposed scores: B[n=q0+lm][k=d=lq*8+j]
    short8 qfrag = *(const short8*)&Qb[(size_t)(b * S + q0 + lm) * 256 + h * 32 + lq * 8];

    short8 ones;
    #pragma unroll
    for (int j = 0; j < 8; ++j) ones[j] = (short)0x3F80;  // bf16 1.0

    f32x4 o0 = {0.f, 0.f, 0.f, 0.f}, o1 = {0.f, 0.f, 0.f, 0.f};
    const f32x4 zf = {0.f, 0.f, 0.f, 0.f};
    float l[4] = {0.f, 0.f, 0.f, 0.f};

    const float scale2 = 0.17677669529663687f * 1.4426950408889634f;
    const float M_ON  = -8.0f * 1.4426950408889634f;
    const float M_OFF = -1.442695e30f;

    // staging: thread -> row tid>>3 (0..31), 4-elem offset (tid&7)*4
    const int srow = tid >> 3, soff = (tid & 7) * 4;
    const unsigned short* kgp = Kb + (size_t)(b * S + srow) * 256 + h * 32 + soff;
    const unsigned short* vgp = Vt + (size_t)(bh * 32 + srow) * S + soff;
    const int sst = srow * LDK + soff;

    // compute-side frag offsets
    const int f0 = lm * LDK + lq * 8;
    const int f1 = (16 + lm) * LDK + lq * 8;
    const int* mp0 = mask + b * S + lq * 4;
    const int* mp1 = mp0 + 16;

    unsigned short* pw = p_lds[wv];
    const int pst = lm * LDP + lq * 4;
    const int prd = lm * LDP + lq * 8;

    const int NC = S / 32;

    // prologue: stage chunk 0 into buffer 0
    {
        uint2 kv = *(const uint2*)kgp;
        uint2 vv = *(const uint2*)vgp;
        *(uint2*)&k_lds[0][sst] = kv;
        *(uint2*)&v_lds[0][sst] = vv;
    }
    __syncthreads();

    for (int c = 0; c < NC; ++c) {
        const int buf = c & 1;

        // issue next chunk's global loads (latency hidden behind compute)
        uint2 knext, vnext;
        if (c + 1 < NC) {
            knext = *(const uint2*)(kgp + (size_t)(c + 1) * 32 * 256);
            vnext = *(const uint2*)(vgp + (c + 1) * 32);
        }

        // scores transposed: D[m=key][n=query]
        short8 kf0 = *(const short8*)&k_lds[buf][f0];
        short8 kf1 = *(const short8*)&k_lds[buf][f1];
        f32x4 s0 = __builtin_amdgcn_mfma_f32_16x16x32_bf16(kf0, qfrag, zf, 0, 0, 0);
        f32x4 s1 = __builtin_amdgcn_mfma_f32_16x16x32_bf16(kf1, qfrag, zf, 0, 0, 0);

        int4 ml0 = *(const int4*)(mp0 + c * 32);
        int4 ml1 = *(const int4*)(mp1 + c * 32);

        float p[8];
        p[0] = exp2f(fmaf(s0[0], scale2, ml0.x ? M_ON : M_OFF));
        p[1] = exp2f(fmaf(s0[1], scale2, ml0.y ? M_ON : M_OFF));
        p[2] = exp2f(fmaf(s0[2], scale2, ml0.z ? M_ON : M_OFF));
        p[3] = exp2f(fmaf(s0[3], scale2, ml0.w ? M_ON : M_OFF));
        p[4] = exp2f(fmaf(s1[0], scale2, ml1.x ? M_ON : M_OFF));
        p[5] = exp2f(fmaf(s1[1], scale2, ml1.y ? M_ON : M_OFF));
        p[6] = exp2f(fmaf(s1[2], scale2, ml1.z ? M_ON : M_OFF));
        p[7] = exp2f(fmaf(s1[3], scale2, ml1.w ? M_ON : M_OFF));

        // P store: [query=lm][keys 4lq..+3, 16+4lq..+3] packed bf16
        uint2 w0, w1;
        w0.x = pack_bf16_tr(p[0], p[1]); w0.y = pack_bf16_tr(p[2], p[3]);
        w1.x = pack_bf16_tr(p[4], p[5]); w1.y = pack_bf16_tr(p[6], p[7]);
        *(uint2*)&pw[pst] = w0;
        *(uint2*)&pw[pst + 16] = w1;

        // read back as A-frag (wave-private, no barrier needed)
        short8 pA = *(const short8*)&pw[prd];

        short8 bv0 = *(const short8*)&v_lds[buf][f0];
        short8 bv1 = *(const short8*)&v_lds[buf][f1];
        f32x4 lf = __builtin_amdgcn_mfma_f32_16x16x32_bf16(pA, ones, zf, 0, 0, 0);
        o0 = __builtin_amdgcn_mfma_f32_16x16x32_bf16(pA, bv0, o0, 0, 0, 0);
        o1 = __builtin_amdgcn_mfma_f32_16x16x32_bf16(pA, bv1, o1, 0, 0, 0);
        #pragma unroll
        for (int r = 0; r < 4; ++r) l[r] += lf[r];

        // write next chunk into the other buffer, then barrier
        if (c + 1 < NC) {
            *(uint2*)&k_lds[buf ^ 1][sst] = knext;
            *(uint2*)&v_lds[buf ^ 1][sst] = vnext;
        }
        __syncthreads();
    }

    #pragma unroll
    for (int r = 0; r < 4; ++r) {
        float inv = 1.0f / l[r];
        size_t base = (size_t)(b * S + q0 + lq * 4 + r) * 256 + h * 32;
        Out[base + lm] = o0[r] * inv;
        Out[base + 16 + lm] = o1[r] * inv;
    }
}

extern "C" void kernel_launch(void* const* d_in, const int* in_sizes, int n_in,
                              void* d_out, int out_size, void* d_ws, size_t ws_size,
                              hipStream_t stream) {
    (void)in_sizes; (void)n_in; (void)out_size; (void)ws_size;
    const float* x    = (const float*)d_in[0];
    const float* ln1g = (const float*)d_in[1];
    const float* ln1b = (const float*)d_in[2];
    const float* Wq   = (const float*)d_in[3];
    const float* bq   = (const float*)d_in[4];
    const float* Wk   = (const float*)d_in[5];
    const float* bk   = (const float*)d_in[6];
    const float* Wv   = (const float*)d_in[7];
    const float* bv   = (const float*)d_in[8];
    const float* ln2g = (const float*)d_in[9];
    const float* ln2b = (const float*)d_in[10];
    const float* Wo1  = (const float*)d_in[11];
    const float* bo1  = (const float*)d_in[12];
    const float* Wo2  = (const float*)d_in[13];
    const float* bo2  = (const float*)d_in[14];
    const int*   mask = (const int*)d_in[15];
    float* out = (float*)d_out;

    const int S = SS, H = HH;
    const int T = BB * SS;                 // 8192 tokens
    const size_t NE = (size_t)T * DD;      // 2M elements
    float* ws    = (float*)d_ws;
    float* attn  = ws + 0 * NE;            // fp32 attn out; holds tk/tv (bf16) earlier
    float* resid = ws + 1 * NE;
    unsigned short* q_bf   = (unsigned short*)(ws + 2 * NE);
    unsigned short* k_bf   = q_bf + NE;
    unsigned short* v_bf   = k_bf + NE;
    unsigned short* h_bf   = v_bf + NE;
    unsigned short* tq_bf  = h_bf + NE;    // layer-1 q out; later MLP tmp
    unsigned short* wt     = tq_bf + NE;
    unsigned short* tk_bf  = (unsigned short*)attn;       // dead before attn writes
    unsigned short* tv_bf  = tk_bf + NE;
    const int WC = 3 * DD * DD;            // 196608
    const int WM = DD * DD;
    unsigned short* wtq0 = wt;
    unsigned short* wtq1 = wt + WC;
    unsigned short* wtk0 = wt + 2 * WC;
    unsigned short* wtk1 = wt + 3 * WC;
    unsigned short* wtv0 = wt + 4 * WC;
    unsigned short* wtv1 = wt + 5 * WC;
    unsigned short* wto1 = wt + 6 * WC;
    unsigned short* wto2 = wt + 6 * WC + WM;
    unsigned short* vt_g = wt + 6 * WC + 2 * WM;  // transposed V [B*H*32][S]

    const int GC = (768 / 32) * (256 / 32);
    const int GM = (256 / 32) * (256 / 32);
    wprep_kernel<<<GC, 256, 0, stream>>>(Wq,      wtq0, 768);
    wprep_kernel<<<GC, 256, 0, stream>>>(Wq + WC, wtq1, 768);
    wprep_kernel<<<GC, 256, 0, stream>>>(Wk,      wtk0, 768);
    wprep_kernel<<<GC, 256, 0, stream>>>(Wk + WC, wtk1, 768);
    wprep_kernel<<<GC, 256, 0, stream>>>(Wv,      wtv0, 768);
    wprep_kernel<<<GC, 256, 0, stream>>>(Wv + WC, wtv1, 768);
    wprep_kernel<<<GM, 256, 0, stream>>>(Wo1,     wto1, 256);
    wprep_kernel<<<GM, 256, 0, stream>>>(Wo2,     wto2, 256);

    // LN1 -> bf16
    ln_kernel<false><<<T, 256, 0, stream>>>(x, nullptr, ln1g, ln1b, nullptr, h_bf);

    const int CG1 = (T / 32) * 3;
    const int CG  = T / 32;

    // temporal encoders, fused across q/k/v
    convf_kernel<3, true, 3, 0><<<CG1, 256, 0, stream>>>(
        h_bf, h_bf, h_bf, wtq0, wtk0, wtv0, bq, bk, bv,
        tq_bf, tk_bf, tv_bf, nullptr, nullptr, S);
    convf_kernel<3, false, 3, 0><<<CG1, 256, 0, stream>>>(
        tq_bf, tk_bf, tv_bf, wtq1, wtk1, wtv1, bq + DD, bk + DD, bv + DD,
        q_bf, k_bf, v_bf, nullptr, nullptr, S);

    // V transpose for attention
    vtrans_kernel<<<BB * H * (S / 32), 256, 0, stream>>>(v_bf, vt_g, S);

    // MFMA attention -> attn (fp32)
    attn_mfma_kernel<<<BB * H * (S / 64), 256, 0, stream>>>(q_bf, k_bf, vt_g, mask, attn, S, H);

    // residual + LN2
    ln_kernel<true><<<T, 256, 0, stream>>>(x, attn, ln2g, ln2b, resid, h_bf);

    // output MLP
    convf_kernel<1, true, 1, 0><<<CG, 256, 0, stream>>>(
        h_bf, nullptr, nullptr, wto1, nullptr, nullptr, bo1, nullptr, nullptr,
        tq_bf, nullptr, nullptr, nullptr, nullptr, S);
    convf_kernel<1, false, 1, 2><<<CG, 256, 0, stream>>>(
        tq_bf, nullptr, nullptr, wto2, nullptr, nullptr, bo2, nullptr, nullptr,
        nullptr, nullptr, nullptr, resid, out, S);
}

// Round 8
// 278.997 us; speedup vs baseline: 1.2874x; 1.0648x over previous
//
#include <hip/hip_runtime.h>
#include <hip/hip_bf16.h>
#include <math.h>

// Problem constants
#define BB 4
#define SS 2048
#define DD 256
#define HH 8
#define HSZ 32

typedef __attribute__((ext_vector_type(8))) short short8;   // 8 bf16 (4 VGPRs)
typedef __attribute__((ext_vector_type(4))) float f32x4;    // MFMA C/D frag

__device__ __forceinline__ float gelu_f(float x) {
    float x3 = x * x * x;
    float z = 0.7978845608028654f * fmaf(0.044715f, x3, x);
    float e = __expf(2.0f * z);
    float t = 1.0f - 2.0f / (e + 1.0f);
    return 0.5f * x * (1.0f + t);
}

__device__ __forceinline__ unsigned short f2bf(float f) {
    unsigned int u = __float_as_uint(f);
    u = (u + 0x7fffu + ((u >> 16) & 1u)) >> 16;
    return (unsigned short)u;
}

// pack two fp32 -> two bf16 (truncation; bias cancels in softmax p/sum(p))
__device__ __forceinline__ unsigned int pack_bf16_tr(float a, float b) {
    return (__float_as_uint(a) >> 16) | (__float_as_uint(b) & 0xffff0000u);
}

// ---------------- Fused weight prep: all 8 transposes in one dispatch ----------------
// segments 0..5: conv layers [768][256] (192 blocks each); 6..7: mats [256][256] (64 each)
__global__ __launch_bounds__(256) void wprep_all_kernel(
    const float* __restrict__ Wq, const float* __restrict__ Wk,
    const float* __restrict__ Wv, const float* __restrict__ Wo1,
    const float* __restrict__ Wo2, unsigned short* __restrict__ wt)
{
    const int WCp = 3 * DD * DD;   // 196608 elems per conv layer
    const int WMp = DD * DD;
    const float* src; unsigned short* dst; int R, rel;
    int i = blockIdx.x;
    if (i < 1152) {
        int seg = i / 192; rel = i % 192; R = 768;
        src = seg == 0 ? Wq : seg == 1 ? Wq + WCp : seg == 2 ? Wk :
              seg == 3 ? Wk + WCp : seg == 4 ? Wv : Wv + WCp;
        dst = wt + (size_t)seg * WCp;
    } else {
        int j = i - 1152; int seg = j / 64; rel = j % 64; R = 256;
        src = seg == 0 ? Wo1 : Wo2;
        dst = wt + (size_t)6 * WCp + (size_t)seg * WMp;
    }
    __shared__ unsigned short t[32][33];
    const int tx = threadIdx.x & 31, ty = threadIdx.x >> 5;
    const int r0 = (rel / 8) * 32, c0 = (rel % 8) * 32;
    #pragma unroll
    for (int j = 0; j < 32; j += 8)
        t[ty + j][tx] = f2bf(src[(r0 + ty + j) * 256 + c0 + tx]);
    __syncthreads();
    #pragma unroll
    for (int j = 0; j < 32; j += 8)
        dst[(size_t)(c0 + ty + j) * R + r0 + tx] = t[tx][ty + j];
}

// ---------------- V transpose: v_bf [B*S][256] -> Vt [B*H*32 d][S] ----------------
__global__ __launch_bounds__(256) void vtrans_kernel(
    const unsigned short* __restrict__ v_bf, unsigned short* __restrict__ Vt, int S)
{
    __shared__ unsigned short t[32][34];
    const int stiles = S / 32;
    const int bh = blockIdx.x / stiles;
    const int s0 = (blockIdx.x % stiles) * 32;
    const int b = bh / HH, h = bh % HH;
    const int d = threadIdx.x & 31, sl = threadIdx.x >> 5;
    #pragma unroll
    for (int j = 0; j < 32; j += 8)
        t[sl + j][d] = v_bf[(size_t)(b * S + s0 + sl + j) * 256 + h * 32 + d];
    __syncthreads();
    const int sw = threadIdx.x & 31, dw = threadIdx.x >> 5;
    #pragma unroll
    for (int j = 0; j < 32; j += 8)
        Vt[(size_t)(bh * 32 + dw + j) * S + s0 + sw] = t[sw][dw + j];
}

// ---------------- LayerNorm, bf16 out (optionally fused residual add) ----------------
template<bool HASRES>
__global__ __launch_bounds__(256) void ln_kernel(
    const float* __restrict__ x, const float* __restrict__ addin,
    const float* __restrict__ g, const float* __restrict__ bvec,
    float* __restrict__ resid_out, unsigned short* __restrict__ oln_bf)
{
    int t = blockIdx.x, i = threadIdx.x;
    int idx = t * DD + i;
    float v = x[idx];
    if (HASRES) {
        v += addin[idx];
        resid_out[idx] = v;
    }
    __shared__ float red[256];
    red[i] = v;
    __syncthreads();
    for (int st = 128; st > 0; st >>= 1) {
        if (i < st) red[i] += red[i + st];
        __syncthreads();
    }
    float mean = red[0] * (1.0f / 256.0f);
    __syncthreads();
    float dv = v - mean;
    red[i] = dv * dv;
    __syncthreads();
    for (int st = 128; st > 0; st >>= 1) {
        if (i < st) red[i] += red[i + st];
        __syncthreads();
    }
    float var = red[0] * (1.0f / 256.0f);
    float r = rsqrtf(var + 1e-6f);
    oln_bf[idx] = f2bf(dv * r * g[i] + bvec[i]);
}

// ---------------- Conv1d as bf16 MFMA implicit GEMM, 32-token tiles ----------------
// K-loop software-pipelined: iteration i+1's B-frags loaded before i's MFMAs.
template<int KS, bool GELU_OUT, int NSETS, int OUTMODE>
__global__ __launch_bounds__(256) void convf_kernel(
    const unsigned short* __restrict__ in0, const unsigned short* __restrict__ in1,
    const unsigned short* __restrict__ in2,
    const unsigned short* __restrict__ W0, const unsigned short* __restrict__ W1,
    const unsigned short* __restrict__ W2,
    const float* __restrict__ bias0, const float* __restrict__ bias1,
    const float* __restrict__ bias2,
    unsigned short* __restrict__ ob0, unsigned short* __restrict__ ob1,
    unsigned short* __restrict__ ob2,
    const float* __restrict__ res, float* __restrict__ outf, int S)
{
    constexpr int TSM = 32;
    constexpr int R = TSM + KS - 1;
    constexpr int pad = (KS - 1) / 2;
    constexpr int KD = KS * 256;
    constexpr int LDW = 264;
    __shared__ __align__(16) unsigned short in_lds[R][LDW];

    int set, tile;
    if (NSETS == 3) { set = blockIdx.x % 3; tile = blockIdx.x / 3; }
    else           { set = 0;              tile = blockIdx.x; }
    const unsigned short* in   = set == 0 ? in0 : (set == 1 ? in1 : in2);
    const unsigned short* Wt   = set == 0 ? W0  : (set == 1 ? W1  : W2);
    const float* bias          = set == 0 ? bias0 : (set == 1 ? bias1 : bias2);
    unsigned short* outb       = set == 0 ? ob0 : (set == 1 ? ob1 : ob2);

    const int tid = threadIdx.x;
    const int lane = tid & 63, wv = tid >> 6;
    const int lm = lane & 15, lq = lane >> 4;
    const int tpb = S / TSM;
    const int b = tile / tpb;
    const int s0 = (tile % tpb) * TSM;

    for (int i = tid; i < R * 32; i += 256) {
        int r = i >> 5, c8 = (i & 31) << 3;
        int s = s0 + r - pad;
        int4 val = make_int4(0, 0, 0, 0);
        if (s >= 0 && s < S)
            val = *(const int4*)&in[(size_t)(b * S + s) * 256 + c8];
        *(int4*)&in_lds[r][c8] = val;
    }

    f32x4 acc[2][4];
    #pragma unroll
    for (int mt = 0; mt < 2; ++mt)
        #pragma unroll
        for (int nt = 0; nt < 4; ++nt) acc[mt][nt] = (f32x4){0.f, 0.f, 0.f, 0.f};

    const int n0 = wv * 64;
    // B pointer: row n0 + nt*16 + lm, col it*32 + lq*8 (kcol is linear in it)
    const unsigned short* wp = Wt + (size_t)(n0 + lm) * KD + lq * 8;

    constexpr int NIT = KS * 8;
    short8 bcur[4];
    #pragma unroll
    for (int nt = 0; nt < 4; ++nt)
        bcur[nt] = *(const short8*)(wp + (size_t)nt * 16 * KD);

    __syncthreads();
    #pragma unroll 4
    for (int it = 0; it < NIT; ++it) {
        const int kk = it >> 3;
        const int icc = (it & 7) * 32 + lq * 8;
        short8 a0 = *(const short8*)&in_lds[kk + lm][icc];
        short8 a1 = *(const short8*)&in_lds[kk + 16 + lm][icc];
        short8 bnx[4];
        if (it + 1 < NIT) {
            const unsigned short* wn = wp + (it + 1) * 32;
            #pragma unroll
            for (int nt = 0; nt < 4; ++nt)
                bnx[nt] = *(const short8*)(wn + (size_t)nt * 16 * KD);
        }
        #pragma unroll
        for (int nt = 0; nt < 4; ++nt) {
            acc[0][nt] = __builtin_amdgcn_mfma_f32_16x16x32_bf16(a0, bcur[nt], acc[0][nt], 0, 0, 0);
            acc[1][nt] = __builtin_amdgcn_mfma_f32_16x16x32_bf16(a1, bcur[nt], acc[1][nt], 0, 0, 0);
        }
        #pragma unroll
        for (int nt = 0; nt < 4; ++nt) bcur[nt] = bnx[nt];
    }

    #pragma unroll
    for (int mt = 0; mt < 2; ++mt) {
        #pragma unroll
        for (int nt = 0; nt < 4; ++nt) {
            int o = n0 + nt * 16 + lm;
            float bv = bias[o];
            #pragma unroll
            for (int r = 0; r < 4; ++r) {
                int t = s0 + mt * 16 + lq * 4 + r;
                float val = acc[mt][nt][r] + bv;
                if (GELU_OUT) val = gelu_f(val);
                size_t idx = (size_t)(b * S + t) * 256 + o;
                if (OUTMODE == 0) outb[idx] = f2bf(val);
                else outf[idx] = val + res[idx];
            }
        }
    }
}

// ---------------- MFMA flash attention v4 (round-7 verified, unchanged) ----------------
__global__ __launch_bounds__(256) void attn_mfma_kernel(
    const unsigned short* __restrict__ Qb, const unsigned short* __restrict__ Kb,
    const unsigned short* __restrict__ Vt, const int* __restrict__ mask,
    float* __restrict__ Out, int S, int H)
{
    constexpr int LDK = 40;
    constexpr int LDP = 40;
    __shared__ __align__(16) unsigned short k_lds[2][32 * LDK];
    __shared__ __align__(16) unsigned short v_lds[2][32 * LDK];
    __shared__ __align__(16) unsigned short p_lds[4][16 * LDP];

    const int qtiles = S / 64;
    const int qt = (blockIdx.x % qtiles) * 64;
    const int bh = blockIdx.x / qtiles;
    const int b = bh / H, h = bh % H;
    const int tid = threadIdx.x;
    const int lane = tid & 63, wv = tid >> 6;
    const int lm = lane & 15, lq = lane >> 4;
    const int q0 = qt + wv * 16;

    short8 qfrag = *(const short8*)&Qb[(size_t)(b * S + q0 + lm) * 256 + h * 32 + lq * 8];

    short8 ones;
    #pragma unroll
    for (int j = 0; j < 8; ++j) ones[j] = (short)0x3F80;  // bf16 1.0

    f32x4 o0 = {0.f, 0.f, 0.f, 0.f}, o1 = {0.f, 0.f, 0.f, 0.f};
    const f32x4 zf = {0.f, 0.f, 0.f, 0.f};
    float l[4] = {0.f, 0.f, 0.f, 0.f};

    const float scale2 = 0.17677669529663687f * 1.4426950408889634f;
    const float M_ON  = -8.0f * 1.4426950408889634f;
    const float M_OFF = -1.442695e30f;

    const int srow = tid >> 3, soff = (tid & 7) * 4;
    const unsigned short* kgp = Kb + (size_t)(b * S + srow) * 256 + h * 32 + soff;
    const unsigned short* vgp = Vt + (size_t)(bh * 32 + srow) * S + soff;
    const int sst = srow * LDK + soff;

    const int f0 = lm * LDK + lq * 8;
    const int f1 = (16 + lm) * LDK + lq * 8;
    const int* mp0 = mask + b * S + lq * 4;
    const int* mp1 = mp0 + 16;

    unsigned short* pw = p_lds[wv];
    const int pst = lm * LDP + lq * 4;
    const int prd = lm * LDP + lq * 8;

    const int NC = S / 32;

    {
        uint2 kv = *(const uint2*)kgp;
        uint2 vv = *(const uint2*)vgp;
        *(uint2*)&k_lds[0][sst] = kv;
        *(uint2*)&v_lds[0][sst] = vv;
    }
    __syncthreads();

    for (int c = 0; c < NC; ++c) {
        const int buf = c & 1;

        uint2 knext, vnext;
        if (c + 1 < NC) {
            knext = *(const uint2*)(kgp + (size_t)(c + 1) * 32 * 256);
            vnext = *(const uint2*)(vgp + (c + 1) * 32);
        }

        short8 kf0 = *(const short8*)&k_lds[buf][f0];
        short8 kf1 = *(const short8*)&k_lds[buf][f1];
        f32x4 s0 = __builtin_amdgcn_mfma_f32_16x16x32_bf16(kf0, qfrag, zf, 0, 0, 0);
        f32x4 s1 = __builtin_amdgcn_mfma_f32_16x16x32_bf16(kf1, qfrag, zf, 0, 0, 0);

        int4 ml0 = *(const int4*)(mp0 + c * 32);
        int4 ml1 = *(const int4*)(mp1 + c * 32);

        float p[8];
        p[0] = exp2f(fmaf(s0[0], scale2, ml0.x ? M_ON : M_OFF));
        p[1] = exp2f(fmaf(s0[1], scale2, ml0.y ? M_ON : M_OFF));
        p[2] = exp2f(fmaf(s0[2], scale2, ml0.z ? M_ON : M_OFF));
        p[3] = exp2f(fmaf(s0[3], scale2, ml0.w ? M_ON : M_OFF));
        p[4] = exp2f(fmaf(s1[0], scale2, ml1.x ? M_ON : M_OFF));
        p[5] = exp2f(fmaf(s1[1], scale2, ml1.y ? M_ON : M_OFF));
        p[6] = exp2f(fmaf(s1[2], scale2, ml1.z ? M_ON : M_OFF));
        p[7] = exp2f(fmaf(s1[3], scale2, ml1.w ? M_ON : M_OFF));

        uint2 w0, w1;
        w0.x = pack_bf16_tr(p[0], p[1]); w0.y = pack_bf16_tr(p[2], p[3]);
        w1.x = pack_bf16_tr(p[4], p[5]); w1.y = pack_bf16_tr(p[6], p[7]);
        *(uint2*)&pw[pst] = w0;
        *(uint2*)&pw[pst + 16] = w1;

        short8 pA = *(const short8*)&pw[prd];

        short8 bv0 = *(const short8*)&v_lds[buf][f0];
        short8 bv1 = *(const short8*)&v_lds[buf][f1];
        f32x4 lf = __builtin_amdgcn_mfma_f32_16x16x32_bf16(pA, ones, zf, 0, 0, 0);
        o0 = __builtin_amdgcn_mfma_f32_16x16x32_bf16(pA, bv0, o0, 0, 0, 0);
        o1 = __builtin_amdgcn_mfma_f32_16x16x32_bf16(pA, bv1, o1, 0, 0, 0);
        #pragma unroll
        for (int r = 0; r < 4; ++r) l[r] += lf[r];

        if (c + 1 < NC) {
            *(uint2*)&k_lds[buf ^ 1][sst] = knext;
            *(uint2*)&v_lds[buf ^ 1][sst] = vnext;
        }
        __syncthreads();
    }

    #pragma unroll
    for (int r = 0; r < 4; ++r) {
        float inv = 1.0f / l[r];
        size_t base = (size_t)(b * S + q0 + lq * 4 + r) * 256 + h * 32;
        Out[base + lm] = o0[r] * inv;
        Out[base + 16 + lm] = o1[r] * inv;
    }
}

extern "C" void kernel_launch(void* const* d_in, const int* in_sizes, int n_in,
                              void* d_out, int out_size, void* d_ws, size_t ws_size,
                              hipStream_t stream) {
    (void)in_sizes; (void)n_in; (void)out_size; (void)ws_size;
    const float* x    = (const float*)d_in[0];
    const float* ln1g = (const float*)d_in[1];
    const float* ln1b = (const float*)d_in[2];
    const float* Wq   = (const float*)d_in[3];
    const float* bq   = (const float*)d_in[4];
    const float* Wk   = (const float*)d_in[5];
    const float* bk   = (const float*)d_in[6];
    const float* Wv   = (const float*)d_in[7];
    const float* bv   = (const float*)d_in[8];
    const float* ln2g = (const float*)d_in[9];
    const float* ln2b = (const float*)d_in[10];
    const float* Wo1  = (const float*)d_in[11];
    const float* bo1  = (const float*)d_in[12];
    const float* Wo2  = (const float*)d_in[13];
    const float* bo2  = (const float*)d_in[14];
    const int*   mask = (const int*)d_in[15];
    float* out = (float*)d_out;

    const int S = SS, H = HH;
    const int T = BB * SS;                 // 8192 tokens
    const size_t NE = (size_t)T * DD;      // 2M elements
    float* ws    = (float*)d_ws;
    float* attn  = ws + 0 * NE;
    float* resid = ws + 1 * NE;
    unsigned short* q_bf   = (unsigned short*)(ws + 2 * NE);
    unsigned short* k_bf   = q_bf + NE;
    unsigned short* v_bf   = k_bf + NE;
    unsigned short* h_bf   = v_bf + NE;
    unsigned short* tq_bf  = h_bf + NE;
    unsigned short* wt     = tq_bf + NE;
    unsigned short* tk_bf  = (unsigned short*)attn;       // dead before attn writes
    unsigned short* tv_bf  = tk_bf + NE;
    const int WC = 3 * DD * DD;            // 196608
    const int WM = DD * DD;
    unsigned short* wtq0 = wt;
    unsigned short* wtq1 = wt + WC;
    unsigned short* wtk0 = wt + 2 * WC;
    unsigned short* wtk1 = wt + 3 * WC;
    unsigned short* wtv0 = wt + 4 * WC;
    unsigned short* wtv1 = wt + 5 * WC;
    unsigned short* wto1 = wt + 6 * WC;
    unsigned short* wto2 = wt + 6 * WC + WM;
    unsigned short* vt_g = wt + 6 * WC + 2 * WM;  // transposed V [B*H*32][S]

    // all weight transposes in one dispatch
    wprep_all_kernel<<<1280, 256, 0, stream>>>(Wq, Wk, Wv, Wo1, Wo2, wt);

    // LN1 -> bf16
    ln_kernel<false><<<T, 256, 0, stream>>>(x, nullptr, ln1g, ln1b, nullptr, h_bf);

    const int CG1 = (T / 32) * 3;
    const int CG  = T / 32;

    // temporal encoders, fused across q/k/v
    convf_kernel<3, true, 3, 0><<<CG1, 256, 0, stream>>>(
        h_bf, h_bf, h_bf, wtq0, wtk0, wtv0, bq, bk, bv,
        tq_bf, tk_bf, tv_bf, nullptr, nullptr, S);
    convf_kernel<3, false, 3, 0><<<CG1, 256, 0, stream>>>(
        tq_bf, tk_bf, tv_bf, wtq1, wtk1, wtv1, bq + DD, bk + DD, bv + DD,
        q_bf, k_bf, v_bf, nullptr, nullptr, S);

    // V transpose for attention
    vtrans_kernel<<<BB * H * (S / 32), 256, 0, stream>>>(v_bf, vt_g, S);

    // MFMA attention -> attn (fp32)
    attn_mfma_kernel<<<BB * H * (S / 64), 256, 0, stream>>>(q_bf, k_bf, vt_g, mask, attn, S, H);

    // residual + LN2
    ln_kernel<true><<<T, 256, 0, stream>>>(x, attn, ln2g, ln2b, resid, h_bf);

    // output MLP
    convf_kernel<1, true, 1, 0><<<CG, 256, 0, stream>>>(
        h_bf, nullptr, nullptr, wto1, nullptr, nullptr, bo1, nullptr, nullptr,
        tq_bf, nullptr, nullptr, nullptr, nullptr, S);
    convf_kernel<1, false, 1, 2><<<CG, 256, 0, stream>>>(
        tq_bf, nullptr, nullptr, wto2, nullptr, nullptr, bo2, nullptr, nullptr,
        nullptr, nullptr, nullptr, resid, out, S);
}

// Round 9
// 266.022 us; speedup vs baseline: 1.3501x; 1.0488x over previous
//
#include <hip/hip_runtime.h>
#include <hip/hip_bf16.h>
#include <math.h>

// Problem constants
#define BB 4
#define SS 2048
#define DD 256
#define HH 8
#define HSZ 32

typedef __attribute__((ext_vector_type(8))) short short8;   // 8 bf16 (4 VGPRs)
typedef __attribute__((ext_vector_type(4))) float f32x4;    // MFMA C/D frag

__device__ __forceinline__ float gelu_f(float x) {
    float x3 = x * x * x;
    float z = 0.7978845608028654f * fmaf(0.044715f, x3, x);
    float e = __expf(2.0f * z);
    float t = 1.0f - 2.0f / (e + 1.0f);
    return 0.5f * x * (1.0f + t);
}

__device__ __forceinline__ unsigned short f2bf(float f) {
    unsigned int u = __float_as_uint(f);
    u = (u + 0x7fffu + ((u >> 16) & 1u)) >> 16;
    return (unsigned short)u;
}

// pack two fp32 -> two bf16 (truncation; bias cancels in softmax p/sum(p))
__device__ __forceinline__ unsigned int pack_bf16_tr(float a, float b) {
    return (__float_as_uint(a) >> 16) | (__float_as_uint(b) & 0xffff0000u);
}

// ---------------- Wave-per-token LayerNorm body (no barriers) ----------------
template<bool HASRES>
__device__ __forceinline__ void ln_wave_body(
    int t, int lane,
    const float* __restrict__ x, const float* __restrict__ addin,
    const float* __restrict__ g, const float* __restrict__ bvec,
    float* __restrict__ resid_out, unsigned short* __restrict__ oln_bf)
{
    const int base = t * DD + lane * 4;
    float4 v4 = *(const float4*)&x[base];
    if (HASRES) {
        float4 a4 = *(const float4*)&addin[base];
        v4.x += a4.x; v4.y += a4.y; v4.z += a4.z; v4.w += a4.w;
        *(float4*)&resid_out[base] = v4;
    }
    float s = (v4.x + v4.y) + (v4.z + v4.w);
    #pragma unroll
    for (int o = 1; o < 64; o <<= 1) s += __shfl_xor(s, o);
    float mean = s * (1.0f / 256.0f);
    float dx = v4.x - mean, dy = v4.y - mean, dz = v4.z - mean, dw = v4.w - mean;
    float q = (dx * dx + dy * dy) + (dz * dz + dw * dw);
    #pragma unroll
    for (int o = 1; o < 64; o <<= 1) q += __shfl_xor(q, o);
    float r = rsqrtf(q * (1.0f / 256.0f) + 1e-6f);
    const float4 g4 = *(const float4*)&g[lane * 4];
    const float4 b4 = *(const float4*)&bvec[lane * 4];
    ushort4 o4;
    o4.x = f2bf(dx * r * g4.x + b4.x);
    o4.y = f2bf(dy * r * g4.y + b4.y);
    o4.z = f2bf(dz * r * g4.z + b4.z);
    o4.w = f2bf(dw * r * g4.w + b4.w);
    *(ushort4*)&oln_bf[base] = o4;
}

template<bool HASRES>
__global__ __launch_bounds__(256) void lnw_kernel(
    const float* __restrict__ x, const float* __restrict__ addin,
    const float* __restrict__ g, const float* __restrict__ bvec,
    float* __restrict__ resid_out, unsigned short* __restrict__ oln_bf)
{
    const int wv = threadIdx.x >> 6, lane = threadIdx.x & 63;
    ln_wave_body<HASRES>(blockIdx.x * 4 + wv, lane, x, addin, g, bvec,
                         resid_out, oln_bf);
}

// ---------------- Fused prep: 8 weight transposes (blocks 0..1279) + LN1 (1280..3327) ----------------
__global__ __launch_bounds__(256) void prep_kernel(
    const float* __restrict__ Wq, const float* __restrict__ Wk,
    const float* __restrict__ Wv, const float* __restrict__ Wo1,
    const float* __restrict__ Wo2, unsigned short* __restrict__ wt,
    const float* __restrict__ x, const float* __restrict__ ln1g,
    const float* __restrict__ ln1b, unsigned short* __restrict__ h_bf)
{
    if (blockIdx.x < 1280) {
        const int WCp = 3 * DD * DD;
        const int WMp = DD * DD;
        const float* src; unsigned short* dst; int R, rel;
        int i = blockIdx.x;
        if (i < 1152) {
            int seg = i / 192; rel = i % 192; R = 768;
            src = seg == 0 ? Wq : seg == 1 ? Wq + WCp : seg == 2 ? Wk :
                  seg == 3 ? Wk + WCp : seg == 4 ? Wv : Wv + WCp;
            dst = wt + (size_t)seg * WCp;
        } else {
            int j = i - 1152; int seg = j / 64; rel = j % 64; R = 256;
            src = seg == 0 ? Wo1 : Wo2;
            dst = wt + (size_t)6 * WCp + (size_t)seg * WMp;
        }
        __shared__ unsigned short t[32][33];
        const int tx = threadIdx.x & 31, ty = threadIdx.x >> 5;
        const int r0 = (rel / 8) * 32, c0 = (rel % 8) * 32;
        #pragma unroll
        for (int j = 0; j < 32; j += 8)
            t[ty + j][tx] = f2bf(src[(r0 + ty + j) * 256 + c0 + tx]);
        __syncthreads();
        #pragma unroll
        for (int j = 0; j < 32; j += 8)
            dst[(size_t)(c0 + ty + j) * R + r0 + tx] = t[tx][ty + j];
    } else {
        const int wv = threadIdx.x >> 6, lane = threadIdx.x & 63;
        ln_wave_body<false>((blockIdx.x - 1280) * 4 + wv, lane,
                            x, nullptr, ln1g, ln1b, nullptr, h_bf);
    }
}

// ---------------- Conv1d as bf16 MFMA implicit GEMM, 32-token tiles ----------------
// K-loop software-pipelined. VTOUT: set 2 writes transposed V (Vt[b*256+ch][S])
// via in-LDS transpose instead of row-major bf16 output.
template<int KS, bool GELU_OUT, int NSETS, int OUTMODE, bool VTOUT>
__global__ __launch_bounds__(256) void convf_kernel(
    const unsigned short* __restrict__ in0, const unsigned short* __restrict__ in1,
    const unsigned short* __restrict__ in2,
    const unsigned short* __restrict__ W0, const unsigned short* __restrict__ W1,
    const unsigned short* __restrict__ W2,
    const float* __restrict__ bias0, const float* __restrict__ bias1,
    const float* __restrict__ bias2,
    unsigned short* __restrict__ ob0, unsigned short* __restrict__ ob1,
    unsigned short* __restrict__ ob2,
    const float* __restrict__ res, float* __restrict__ outf, int S)
{
    constexpr int TSM = 32;
    constexpr int R = TSM + KS - 1;
    constexpr int pad = (KS - 1) / 2;
    constexpr int KD = KS * 256;
    constexpr int LDW = 264;
    constexpr int TRS = 256 * 40;  // transpose staging (elems), stride 40
    constexpr int SME = VTOUT ? (R * LDW > TRS ? R * LDW : TRS) : R * LDW;
    __shared__ __align__(16) unsigned short smem[SME];
    unsigned short (*in_lds)[LDW] = (unsigned short (*)[LDW])smem;

    int set, tile;
    if (NSETS == 3) { set = blockIdx.x % 3; tile = blockIdx.x / 3; }
    else           { set = 0;              tile = blockIdx.x; }
    const unsigned short* in   = set == 0 ? in0 : (set == 1 ? in1 : in2);
    const unsigned short* Wt   = set == 0 ? W0  : (set == 1 ? W1  : W2);
    const float* bias          = set == 0 ? bias0 : (set == 1 ? bias1 : bias2);
    unsigned short* outb       = set == 0 ? ob0 : (set == 1 ? ob1 : ob2);

    const int tid = threadIdx.x;
    const int lane = tid & 63, wv = tid >> 6;
    const int lm = lane & 15, lq = lane >> 4;
    const int tpb = S / TSM;
    const int b = tile / tpb;
    const int s0 = (tile % tpb) * TSM;

    for (int i = tid; i < R * 32; i += 256) {
        int r = i >> 5, c8 = (i & 31) << 3;
        int s = s0 + r - pad;
        int4 val = make_int4(0, 0, 0, 0);
        if (s >= 0 && s < S)
            val = *(const int4*)&in[(size_t)(b * S + s) * 256 + c8];
        *(int4*)&in_lds[r][c8] = val;
    }

    f32x4 acc[2][4];
    #pragma unroll
    for (int mt = 0; mt < 2; ++mt)
        #pragma unroll
        for (int nt = 0; nt < 4; ++nt) acc[mt][nt] = (f32x4){0.f, 0.f, 0.f, 0.f};

    const int n0 = wv * 64;
    const unsigned short* wp = Wt + (size_t)(n0 + lm) * KD + lq * 8;

    constexpr int NIT = KS * 8;
    short8 bcur[4];
    #pragma unroll
    for (int nt = 0; nt < 4; ++nt)
        bcur[nt] = *(const short8*)(wp + (size_t)nt * 16 * KD);

    __syncthreads();
    #pragma unroll 4
    for (int it = 0; it < NIT; ++it) {
        const int kk = it >> 3;
        const int icc = (it & 7) * 32 + lq * 8;
        short8 a0 = *(const short8*)&in_lds[kk + lm][icc];
        short8 a1 = *(const short8*)&in_lds[kk + 16 + lm][icc];
        short8 bnx[4];
        if (it + 1 < NIT) {
            const unsigned short* wn = wp + (it + 1) * 32;
            #pragma unroll
            for (int nt = 0; nt < 4; ++nt)
                bnx[nt] = *(const short8*)(wn + (size_t)nt * 16 * KD);
        }
        #pragma unroll
        for (int nt = 0; nt < 4; ++nt) {
            acc[0][nt] = __builtin_amdgcn_mfma_f32_16x16x32_bf16(a0, bcur[nt], acc[0][nt], 0, 0, 0);
            acc[1][nt] = __builtin_amdgcn_mfma_f32_16x16x32_bf16(a1, bcur[nt], acc[1][nt], 0, 0, 0);
        }
        #pragma unroll
        for (int nt = 0; nt < 4; ++nt) bcur[nt] = bnx[nt];
    }

    if (VTOUT && set == 2) {
        // transpose epilogue: acc -> smem[ch][tok] -> Vt[b*256+ch][s0..s0+31]
        __syncthreads();  // all waves done reading in_lds
        #pragma unroll
        for (int mt = 0; mt < 2; ++mt)
            #pragma unroll
            for (int nt = 0; nt < 4; ++nt) {
                int ch = n0 + nt * 16 + lm;
                float bv = bias[ch];
                #pragma unroll
                for (int r = 0; r < 4; ++r) {
                    int tok = mt * 16 + lq * 4 + r;
                    smem[ch * 40 + tok] = f2bf(acc[mt][nt][r] + bv);
                }
            }
        __syncthreads();
        int ch = tid;
        size_t row = ((size_t)b * 256 + ch) * S + s0;
        #pragma unroll
        for (int j = 0; j < 4; ++j) {
            uint2 lo = *(const uint2*)&smem[ch * 40 + j * 8];
            uint2 hi = *(const uint2*)&smem[ch * 40 + j * 8 + 4];
            *(int4*)&outb[row + j * 8] = make_int4(lo.x, lo.y, hi.x, hi.y);
        }
    } else {
        #pragma unroll
        for (int mt = 0; mt < 2; ++mt) {
            #pragma unroll
            for (int nt = 0; nt < 4; ++nt) {
                int o = n0 + nt * 16 + lm;
                float bv = bias[o];
                #pragma unroll
                for (int r = 0; r < 4; ++r) {
                    int t = s0 + mt * 16 + lq * 4 + r;
                    float val = acc[mt][nt][r] + bv;
                    if (GELU_OUT) val = gelu_f(val);
                    size_t idx = (size_t)(b * S + t) * 256 + o;
                    if (OUTMODE == 0) outb[idx] = f2bf(val);
                    else outf[idx] = val + res[idx];
                }
            }
        }
    }
}

// ---------------- MFMA flash attention v4 (round-7 verified, unchanged) ----------------
__global__ __launch_bounds__(256) void attn_mfma_kernel(
    const unsigned short* __restrict__ Qb, const unsigned short* __restrict__ Kb,
    const unsigned short* __restrict__ Vt, const int* __restrict__ mask,
    float* __restrict__ Out, int S, int H)
{
    constexpr int LDK = 40;
    constexpr int LDP = 40;
    __shared__ __align__(16) unsigned short k_lds[2][32 * LDK];
    __shared__ __align__(16) unsigned short v_lds[2][32 * LDK];
    __shared__ __align__(16) unsigned short p_lds[4][16 * LDP];

    const int qtiles = S / 64;
    const int qt = (blockIdx.x % qtiles) * 64;
    const int bh = blockIdx.x / qtiles;
    const int b = bh / H, h = bh % H;
    const int tid = threadIdx.x;
    const int lane = tid & 63, wv = tid >> 6;
    const int lm = lane & 15, lq = lane >> 4;
    const int q0 = qt + wv * 16;

    short8 qfrag = *(const short8*)&Qb[(size_t)(b * S + q0 + lm) * 256 + h * 32 + lq * 8];

    short8 ones;
    #pragma unroll
    for (int j = 0; j < 8; ++j) ones[j] = (short)0x3F80;  // bf16 1.0

    f32x4 o0 = {0.f, 0.f, 0.f, 0.f}, o1 = {0.f, 0.f, 0.f, 0.f};
    const f32x4 zf = {0.f, 0.f, 0.f, 0.f};
    float l[4] = {0.f, 0.f, 0.f, 0.f};

    const float scale2 = 0.17677669529663687f * 1.4426950408889634f;
    const float M_ON  = -8.0f * 1.4426950408889634f;
    const float M_OFF = -1.442695e30f;

    const int srow = tid >> 3, soff = (tid & 7) * 4;
    const unsigned short* kgp = Kb + (size_t)(b * S + srow) * 256 + h * 32 + soff;
    const unsigned short* vgp = Vt + (size_t)(bh * 32 + srow) * S + soff;
    const int sst = srow * LDK + soff;

    const int f0 = lm * LDK + lq * 8;
    const int f1 = (16 + lm) * LDK + lq * 8;
    const int* mp0 = mask + b * S + lq * 4;
    const int* mp1 = mp0 + 16;

    unsigned short* pw = p_lds[wv];
    const int pst = lm * LDP + lq * 4;
    const int prd = lm * LDP + lq * 8;

    const int NC = S / 32;

    {
        uint2 kv = *(const uint2*)kgp;
        uint2 vv = *(const uint2*)vgp;
        *(uint2*)&k_lds[0][sst] = kv;
        *(uint2*)&v_lds[0][sst] = vv;
    }
    __syncthreads();

    for (int c = 0; c < NC; ++c) {
        const int buf = c & 1;

        uint2 knext, vnext;
        if (c + 1 < NC) {
            knext = *(const uint2*)(kgp + (size_t)(c + 1) * 32 * 256);
            vnext = *(const uint2*)(vgp + (c + 1) * 32);
        }

        short8 kf0 = *(const short8*)&k_lds[buf][f0];
        short8 kf1 = *(const short8*)&k_lds[buf][f1];
        f32x4 s0 = __builtin_amdgcn_mfma_f32_16x16x32_bf16(kf0, qfrag, zf, 0, 0, 0);
        f32x4 s1 = __builtin_amdgcn_mfma_f32_16x16x32_bf16(kf1, qfrag, zf, 0, 0, 0);

        int4 ml0 = *(const int4*)(mp0 + c * 32);
        int4 ml1 = *(const int4*)(mp1 + c * 32);

        float p[8];
        p[0] = exp2f(fmaf(s0[0], scale2, ml0.x ? M_ON : M_OFF));
        p[1] = exp2f(fmaf(s0[1], scale2, ml0.y ? M_ON : M_OFF));
        p[2] = exp2f(fmaf(s0[2], scale2, ml0.z ? M_ON : M_OFF));
        p[3] = exp2f(fmaf(s0[3], scale2, ml0.w ? M_ON : M_OFF));
        p[4] = exp2f(fmaf(s1[0], scale2, ml1.x ? M_ON : M_OFF));
        p[5] = exp2f(fmaf(s1[1], scale2, ml1.y ? M_ON : M_OFF));
        p[6] = exp2f(fmaf(s1[2], scale2, ml1.z ? M_ON : M_OFF));
        p[7] = exp2f(fmaf(s1[3], scale2, ml1.w ? M_ON : M_OFF));

        uint2 w0, w1;
        w0.x = pack_bf16_tr(p[0], p[1]); w0.y = pack_bf16_tr(p[2], p[3]);
        w1.x = pack_bf16_tr(p[4], p[5]); w1.y = pack_bf16_tr(p[6], p[7]);
        *(uint2*)&pw[pst] = w0;
        *(uint2*)&pw[pst + 16] = w1;

        short8 pA = *(const short8*)&pw[prd];

        short8 bv0 = *(const short8*)&v_lds[buf][f0];
        short8 bv1 = *(const short8*)&v_lds[buf][f1];
        f32x4 lf = __builtin_amdgcn_mfma_f32_16x16x32_bf16(pA, ones, zf, 0, 0, 0);
        o0 = __builtin_amdgcn_mfma_f32_16x16x32_bf16(pA, bv0, o0, 0, 0, 0);
        o1 = __builtin_amdgcn_mfma_f32_16x16x32_bf16(pA, bv1, o1, 0, 0, 0);
        #pragma unroll
        for (int r = 0; r < 4; ++r) l[r] += lf[r];

        if (c + 1 < NC) {
            *(uint2*)&k_lds[buf ^ 1][sst] = knext;
            *(uint2*)&v_lds[buf ^ 1][sst] = vnext;
        }
        __syncthreads();
    }

    #pragma unroll
    for (int r = 0; r < 4; ++r) {
        float inv = 1.0f / l[r];
        size_t base = (size_t)(b * S + q0 + lq * 4 + r) * 256 + h * 32;
        Out[base + lm] = o0[r] * inv;
        Out[base + 16 + lm] = o1[r] * inv;
    }
}

extern "C" void kernel_launch(void* const* d_in, const int* in_sizes, int n_in,
                              void* d_out, int out_size, void* d_ws, size_t ws_size,
                              hipStream_t stream) {
    (void)in_sizes; (void)n_in; (void)out_size; (void)ws_size;
    const float* x    = (const float*)d_in[0];
    const float* ln1g = (const float*)d_in[1];
    const float* ln1b = (const float*)d_in[2];
    const float* Wq   = (const float*)d_in[3];
    const float* bq   = (const float*)d_in[4];
    const float* Wk   = (const float*)d_in[5];
    const float* bk   = (const float*)d_in[6];
    const float* Wv   = (const float*)d_in[7];
    const float* bv   = (const float*)d_in[8];
    const float* ln2g = (const float*)d_in[9];
    const float* ln2b = (const float*)d_in[10];
    const float* Wo1  = (const float*)d_in[11];
    const float* bo1  = (const float*)d_in[12];
    const float* Wo2  = (const float*)d_in[13];
    const float* bo2  = (const float*)d_in[14];
    const int*   mask = (const int*)d_in[15];
    float* out = (float*)d_out;

    const int S = SS, H = HH;
    const int T = BB * SS;                 // 8192 tokens
    const size_t NE = (size_t)T * DD;      // 2M elements
    float* ws    = (float*)d_ws;
    float* attn  = ws + 0 * NE;
    float* resid = ws + 1 * NE;
    unsigned short* q_bf   = (unsigned short*)(ws + 2 * NE);
    unsigned short* k_bf   = q_bf + NE;
    unsigned short* h_bf   = k_bf + NE;
    unsigned short* tq_bf  = h_bf + NE;    // layer-1 q out; later MLP tmp
    unsigned short* wt     = tq_bf + NE;
    unsigned short* tk_bf  = (unsigned short*)attn;       // dead before attn writes
    unsigned short* tv_bf  = tk_bf + NE;
    const int WC = 3 * DD * DD;            // 196608
    const int WM = DD * DD;
    unsigned short* wtq0 = wt;
    unsigned short* wtq1 = wt + WC;
    unsigned short* wtk0 = wt + 2 * WC;
    unsigned short* wtk1 = wt + 3 * WC;
    unsigned short* wtv0 = wt + 4 * WC;
    unsigned short* wtv1 = wt + 5 * WC;
    unsigned short* wto1 = wt + 6 * WC;
    unsigned short* wto2 = wt + 6 * WC + WM;
    unsigned short* vt_g = wt + 6 * WC + 2 * WM;  // transposed V [B*256][S]

    // fused: 8 weight transposes + LN1
    prep_kernel<<<1280 + T / 4, 256, 0, stream>>>(
        Wq, Wk, Wv, Wo1, Wo2, wt, x, ln1g, ln1b, h_bf);

    const int CG1 = (T / 32) * 3;
    const int CG  = T / 32;

    // temporal encoders, fused across q/k/v; layer 2's v-set writes Vt directly
    convf_kernel<3, true, 3, 0, false><<<CG1, 256, 0, stream>>>(
        h_bf, h_bf, h_bf, wtq0, wtk0, wtv0, bq, bk, bv,
        tq_bf, tk_bf, tv_bf, nullptr, nullptr, S);
    convf_kernel<3, false, 3, 0, true><<<CG1, 256, 0, stream>>>(
        tq_bf, tk_bf, tv_bf, wtq1, wtk1, wtv1, bq + DD, bk + DD, bv + DD,
        q_bf, k_bf, vt_g, nullptr, nullptr, S);

    // MFMA attention -> attn (fp32; overwrites tk/tv region, already consumed)
    attn_mfma_kernel<<<BB * H * (S / 64), 256, 0, stream>>>(q_bf, k_bf, vt_g, mask, attn, S, H);

    // residual + LN2 (wave-per-token)
    lnw_kernel<true><<<T / 4, 256, 0, stream>>>(x, attn, ln2g, ln2b, resid, h_bf);

    // output MLP
    convf_kernel<1, true, 1, 0, false><<<CG, 256, 0, stream>>>(
        h_bf, nullptr, nullptr, wto1, nullptr, nullptr, bo1, nullptr, nullptr,
        tq_bf, nullptr, nullptr, nullptr, nullptr, S);
    convf_kernel<1, false, 1, 2, false><<<CG, 256, 0, stream>>>(
        tq_bf, nullptr, nullptr, wto2, nullptr, nullptr, bo2, nullptr, nullptr,
        nullptr, nullptr, nullptr, resid, out, S);
}

// Round 10
// 263.496 us; speedup vs baseline: 1.3631x; 1.0096x over previous
//
#include <hip/hip_runtime.h>
#include <hip/hip_bf16.h>
#include <math.h>

// Problem constants
#define BB 4
#define SS 2048
#define DD 256
#define HH 8
#define HSZ 32

typedef __attribute__((ext_vector_type(8))) short short8;   // 8 bf16 (4 VGPRs)
typedef __attribute__((ext_vector_type(4))) float f32x4;    // MFMA C/D frag

__device__ __forceinline__ float gelu_f(float x) {
    float x3 = x * x * x;
    float z = 0.7978845608028654f * fmaf(0.044715f, x3, x);
    float e = __expf(2.0f * z);
    float t = 1.0f - 2.0f / (e + 1.0f);
    return 0.5f * x * (1.0f + t);
}

__device__ __forceinline__ unsigned short f2bf(float f) {
    unsigned int u = __float_as_uint(f);
    u = (u + 0x7fffu + ((u >> 16) & 1u)) >> 16;
    return (unsigned short)u;
}

// pack two fp32 -> two bf16 (truncation; bias cancels in softmax p/sum(p))
__device__ __forceinline__ unsigned int pack_bf16_tr(float a, float b) {
    return (__float_as_uint(a) >> 16) | (__float_as_uint(b) & 0xffff0000u);
}

// ---------------- Wave-per-token LayerNorm body (no barriers) ----------------
template<bool HASRES>
__device__ __forceinline__ void ln_wave_body(
    int t, int lane,
    const float* __restrict__ x, const float* __restrict__ addin,
    const float* __restrict__ g, const float* __restrict__ bvec,
    float* __restrict__ resid_out, unsigned short* __restrict__ oln_bf)
{
    const int base = t * DD + lane * 4;
    float4 v4 = *(const float4*)&x[base];
    if (HASRES) {
        float4 a4 = *(const float4*)&addin[base];
        v4.x += a4.x; v4.y += a4.y; v4.z += a4.z; v4.w += a4.w;
        *(float4*)&resid_out[base] = v4;
    }
    float s = (v4.x + v4.y) + (v4.z + v4.w);
    #pragma unroll
    for (int o = 1; o < 64; o <<= 1) s += __shfl_xor(s, o);
    float mean = s * (1.0f / 256.0f);
    float dx = v4.x - mean, dy = v4.y - mean, dz = v4.z - mean, dw = v4.w - mean;
    float q = (dx * dx + dy * dy) + (dz * dz + dw * dw);
    #pragma unroll
    for (int o = 1; o < 64; o <<= 1) q += __shfl_xor(q, o);
    float r = rsqrtf(q * (1.0f / 256.0f) + 1e-6f);
    const float4 g4 = *(const float4*)&g[lane * 4];
    const float4 b4 = *(const float4*)&bvec[lane * 4];
    ushort4 o4;
    o4.x = f2bf(dx * r * g4.x + b4.x);
    o4.y = f2bf(dy * r * g4.y + b4.y);
    o4.z = f2bf(dz * r * g4.z + b4.z);
    o4.w = f2bf(dw * r * g4.w + b4.w);
    *(ushort4*)&oln_bf[base] = o4;
}

template<bool HASRES>
__global__ __launch_bounds__(256) void lnw_kernel(
    const float* __restrict__ x, const float* __restrict__ addin,
    const float* __restrict__ g, const float* __restrict__ bvec,
    float* __restrict__ resid_out, unsigned short* __restrict__ oln_bf)
{
    const int wv = threadIdx.x >> 6, lane = threadIdx.x & 63;
    ln_wave_body<HASRES>(blockIdx.x * 4 + wv, lane, x, addin, g, bvec,
                         resid_out, oln_bf);
}

// ---------------- Fused prep: 8 weight transposes (blocks 0..1279) + LN1 (1280..3327) ----------------
__global__ __launch_bounds__(256) void prep_kernel(
    const float* __restrict__ Wq, const float* __restrict__ Wk,
    const float* __restrict__ Wv, const float* __restrict__ Wo1,
    const float* __restrict__ Wo2, unsigned short* __restrict__ wt,
    const float* __restrict__ x, const float* __restrict__ ln1g,
    const float* __restrict__ ln1b, unsigned short* __restrict__ h_bf)
{
    if (blockIdx.x < 1280) {
        const int WCp = 3 * DD * DD;
        const int WMp = DD * DD;
        const float* src; unsigned short* dst; int R, rel;
        int i = blockIdx.x;
        if (i < 1152) {
            int seg = i / 192; rel = i % 192; R = 768;
            src = seg == 0 ? Wq : seg == 1 ? Wq + WCp : seg == 2 ? Wk :
                  seg == 3 ? Wk + WCp : seg == 4 ? Wv : Wv + WCp;
            dst = wt + (size_t)seg * WCp;
        } else {
            int j = i - 1152; int seg = j / 64; rel = j % 64; R = 256;
            src = seg == 0 ? Wo1 : Wo2;
            dst = wt + (size_t)6 * WCp + (size_t)seg * WMp;
        }
        __shared__ unsigned short t[32][33];
        const int tx = threadIdx.x & 31, ty = threadIdx.x >> 5;
        const int r0 = (rel / 8) * 32, c0 = (rel % 8) * 32;
        #pragma unroll
        for (int j = 0; j < 32; j += 8)
            t[ty + j][tx] = f2bf(src[(r0 + ty + j) * 256 + c0 + tx]);
        __syncthreads();
        #pragma unroll
        for (int j = 0; j < 32; j += 8)
            dst[(size_t)(c0 + ty + j) * R + r0 + tx] = t[tx][ty + j];
    } else {
        const int wv = threadIdx.x >> 6, lane = threadIdx.x & 63;
        ln_wave_body<false>((blockIdx.x - 1280) * 4 + wv, lane,
                            x, nullptr, ln1g, ln1b, nullptr, h_bf);
    }
}

// ---------------- Conv1d as bf16 MFMA implicit GEMM, 32-token tiles ----------------
// K-loop FULLY UNROLLED with branchless 4-slot circular B prefetch, 3 deep:
// ~12 loads always in flight, fine-grained vmcnt waits (never drains to 0).
// VTOUT: set 2 writes transposed V (Vt[b*256+ch][S]) via in-LDS transpose.
template<int KS, bool GELU_OUT, int NSETS, int OUTMODE, bool VTOUT>
__global__ __launch_bounds__(256) void convf_kernel(
    const unsigned short* __restrict__ in0, const unsigned short* __restrict__ in1,
    const unsigned short* __restrict__ in2,
    const unsigned short* __restrict__ W0, const unsigned short* __restrict__ W1,
    const unsigned short* __restrict__ W2,
    const float* __restrict__ bias0, const float* __restrict__ bias1,
    const float* __restrict__ bias2,
    unsigned short* __restrict__ ob0, unsigned short* __restrict__ ob1,
    unsigned short* __restrict__ ob2,
    const float* __restrict__ res, float* __restrict__ outf, int S)
{
    constexpr int TSM = 32;
    constexpr int R = TSM + KS - 1;
    constexpr int pad = (KS - 1) / 2;
    constexpr int KD = KS * 256;
    constexpr int LDW = 264;
    constexpr int TRS = 256 * 40;  // transpose staging (elems), stride 40
    constexpr int SME = VTOUT ? (R * LDW > TRS ? R * LDW : TRS) : R * LDW;
    __shared__ __align__(16) unsigned short smem[SME];
    unsigned short (*in_lds)[LDW] = (unsigned short (*)[LDW])smem;

    int set, tile;
    if (NSETS == 3) { set = blockIdx.x % 3; tile = blockIdx.x / 3; }
    else           { set = 0;              tile = blockIdx.x; }
    const unsigned short* in   = set == 0 ? in0 : (set == 1 ? in1 : in2);
    const unsigned short* Wt   = set == 0 ? W0  : (set == 1 ? W1  : W2);
    const float* bias          = set == 0 ? bias0 : (set == 1 ? bias1 : bias2);
    unsigned short* outb       = set == 0 ? ob0 : (set == 1 ? ob1 : ob2);

    const int tid = threadIdx.x;
    const int lane = tid & 63, wv = tid >> 6;
    const int lm = lane & 15, lq = lane >> 4;
    const int tpb = S / TSM;
    const int b = tile / tpb;
    const int s0 = (tile % tpb) * TSM;

    for (int i = tid; i < R * 32; i += 256) {
        int r = i >> 5, c8 = (i & 31) << 3;
        int s = s0 + r - pad;
        int4 val = make_int4(0, 0, 0, 0);
        if (s >= 0 && s < S)
            val = *(const int4*)&in[(size_t)(b * S + s) * 256 + c8];
        *(int4*)&in_lds[r][c8] = val;
    }

    f32x4 acc[2][4];
    #pragma unroll
    for (int mt = 0; mt < 2; ++mt)
        #pragma unroll
        for (int nt = 0; nt < 4; ++nt) acc[mt][nt] = (f32x4){0.f, 0.f, 0.f, 0.f};

    const int n0 = wv * 64;
    const unsigned short* wp = Wt + (size_t)(n0 + lm) * KD + lq * 8;

    constexpr int NIT = KS * 8;
    constexpr int PD = (NIT < 3) ? NIT : 3;   // prefetch depth
    short8 bf[4][4];
    #pragma unroll
    for (int p = 0; p < PD; ++p)
        #pragma unroll
        for (int nt = 0; nt < 4; ++nt)
            bf[p][nt] = *(const short8*)(wp + p * 32 + (size_t)nt * 16 * KD);

    __syncthreads();
    #pragma unroll
    for (int it = 0; it < NIT; ++it) {
        if (it + PD < NIT) {   // compile-time under full unroll
            #pragma unroll
            for (int nt = 0; nt < 4; ++nt)
                bf[(it + PD) & 3][nt] =
                    *(const short8*)(wp + (it + PD) * 32 + (size_t)nt * 16 * KD);
        }
        const int kk = it >> 3;
        const int icc = (it & 7) * 32 + lq * 8;
        short8 a0 = *(const short8*)&in_lds[kk + lm][icc];
        short8 a1 = *(const short8*)&in_lds[kk + 16 + lm][icc];
        #pragma unroll
        for (int nt = 0; nt < 4; ++nt) {
            acc[0][nt] = __builtin_amdgcn_mfma_f32_16x16x32_bf16(a0, bf[it & 3][nt], acc[0][nt], 0, 0, 0);
            acc[1][nt] = __builtin_amdgcn_mfma_f32_16x16x32_bf16(a1, bf[it & 3][nt], acc[1][nt], 0, 0, 0);
        }
    }

    if (VTOUT && set == 2) {
        // transpose epilogue: acc -> smem[ch][tok] -> Vt[b*256+ch][s0..s0+31]
        __syncthreads();  // all waves done reading in_lds
        #pragma unroll
        for (int mt = 0; mt < 2; ++mt)
            #pragma unroll
            for (int nt = 0; nt < 4; ++nt) {
                int ch = n0 + nt * 16 + lm;
                float bv = bias[ch];
                #pragma unroll
                for (int r = 0; r < 4; ++r) {
                    int tok = mt * 16 + lq * 4 + r;
                    smem[ch * 40 + tok] = f2bf(acc[mt][nt][r] + bv);
                }
            }
        __syncthreads();
        int ch = tid;
        size_t row = ((size_t)b * 256 + ch) * S + s0;
        #pragma unroll
        for (int j = 0; j < 4; ++j) {
            uint2 lo = *(const uint2*)&smem[ch * 40 + j * 8];
            uint2 hi = *(const uint2*)&smem[ch * 40 + j * 8 + 4];
            *(int4*)&outb[row + j * 8] = make_int4(lo.x, lo.y, hi.x, hi.y);
        }
    } else {
        #pragma unroll
        for (int mt = 0; mt < 2; ++mt) {
            #pragma unroll
            for (int nt = 0; nt < 4; ++nt) {
                int o = n0 + nt * 16 + lm;
                float bv = bias[o];
                #pragma unroll
                for (int r = 0; r < 4; ++r) {
                    int t = s0 + mt * 16 + lq * 4 + r;
                    float val = acc[mt][nt][r] + bv;
                    if (GELU_OUT) val = gelu_f(val);
                    size_t idx = (size_t)(b * S + t) * 256 + o;
                    if (OUTMODE == 0) outb[idx] = f2bf(val);
                    else outf[idx] = val + res[idx];
                }
            }
        }
    }
}

// ---------------- MFMA flash attention v4 (round-7 verified, unchanged) ----------------
__global__ __launch_bounds__(256) void attn_mfma_kernel(
    const unsigned short* __restrict__ Qb, const unsigned short* __restrict__ Kb,
    const unsigned short* __restrict__ Vt, const int* __restrict__ mask,
    float* __restrict__ Out, int S, int H)
{
    constexpr int LDK = 40;
    constexpr int LDP = 40;
    __shared__ __align__(16) unsigned short k_lds[2][32 * LDK];
    __shared__ __align__(16) unsigned short v_lds[2][32 * LDK];
    __shared__ __align__(16) unsigned short p_lds[4][16 * LDP];

    const int qtiles = S / 64;
    const int qt = (blockIdx.x % qtiles) * 64;
    const int bh = blockIdx.x / qtiles;
    const int b = bh / H, h = bh % H;
    const int tid = threadIdx.x;
    const int lane = tid & 63, wv = tid >> 6;
    const int lm = lane & 15, lq = lane >> 4;
    const int q0 = qt + wv * 16;

    short8 qfrag = *(const short8*)&Qb[(size_t)(b * S + q0 + lm) * 256 + h * 32 + lq * 8];

    short8 ones;
    #pragma unroll
    for (int j = 0; j < 8; ++j) ones[j] = (short)0x3F80;  // bf16 1.0

    f32x4 o0 = {0.f, 0.f, 0.f, 0.f}, o1 = {0.f, 0.f, 0.f, 0.f};
    const f32x4 zf = {0.f, 0.f, 0.f, 0.f};
    float l[4] = {0.f, 0.f, 0.f, 0.f};

    const float scale2 = 0.17677669529663687f * 1.4426950408889634f;
    const float M_ON  = -8.0f * 1.4426950408889634f;
    const float M_OFF = -1.442695e30f;

    const int srow = tid >> 3, soff = (tid & 7) * 4;
    const unsigned short* kgp = Kb + (size_t)(b * S + srow) * 256 + h * 32 + soff;
    const unsigned short* vgp = Vt + (size_t)(bh * 32 + srow) * S + soff;
    const int sst = srow * LDK + soff;

    const int f0 = lm * LDK + lq * 8;
    const int f1 = (16 + lm) * LDK + lq * 8;
    const int* mp0 = mask + b * S + lq * 4;
    const int* mp1 = mp0 + 16;

    unsigned short* pw = p_lds[wv];
    const int pst = lm * LDP + lq * 4;
    const int prd = lm * LDP + lq * 8;

    const int NC = S / 32;

    {
        uint2 kv = *(const uint2*)kgp;
        uint2 vv = *(const uint2*)vgp;
        *(uint2*)&k_lds[0][sst] = kv;
        *(uint2*)&v_lds[0][sst] = vv;
    }
    __syncthreads();

    for (int c = 0; c < NC; ++c) {
        const int buf = c & 1;

        uint2 knext, vnext;
        if (c + 1 < NC) {
            knext = *(const uint2*)(kgp + (size_t)(c + 1) * 32 * 256);
            vnext = *(const uint2*)(vgp + (c + 1) * 32);
        }

        short8 kf0 = *(const short8*)&k_lds[buf][f0];
        short8 kf1 = *(const short8*)&k_lds[buf][f1];
        f32x4 s0 = __builtin_amdgcn_mfma_f32_16x16x32_bf16(kf0, qfrag, zf, 0, 0, 0);
        f32x4 s1 = __builtin_amdgcn_mfma_f32_16x16x32_bf16(kf1, qfrag, zf, 0, 0, 0);

        int4 ml0 = *(const int4*)(mp0 + c * 32);
        int4 ml1 = *(const int4*)(mp1 + c * 32);

        float p[8];
        p[0] = exp2f(fmaf(s0[0], scale2, ml0.x ? M_ON : M_OFF));
        p[1] = exp2f(fmaf(s0[1], scale2, ml0.y ? M_ON : M_OFF));
        p[2] = exp2f(fmaf(s0[2], scale2, ml0.z ? M_ON : M_OFF));
        p[3] = exp2f(fmaf(s0[3], scale2, ml0.w ? M_ON : M_OFF));
        p[4] = exp2f(fmaf(s1[0], scale2, ml1.x ? M_ON : M_OFF));
        p[5] = exp2f(fmaf(s1[1], scale2, ml1.y ? M_ON : M_OFF));
        p[6] = exp2f(fmaf(s1[2], scale2, ml1.z ? M_ON : M_OFF));
        p[7] = exp2f(fmaf(s1[3], scale2, ml1.w ? M_ON : M_OFF));

        uint2 w0, w1;
        w0.x = pack_bf16_tr(p[0], p[1]); w0.y = pack_bf16_tr(p[2], p[3]);
        w1.x = pack_bf16_tr(p[4], p[5]); w1.y = pack_bf16_tr(p[6], p[7]);
        *(uint2*)&pw[pst] = w0;
        *(uint2*)&pw[pst + 16] = w1;

        short8 pA = *(const short8*)&pw[prd];

        short8 bv0 = *(const short8*)&v_lds[buf][f0];
        short8 bv1 = *(const short8*)&v_lds[buf][f1];
        f32x4 lf = __builtin_amdgcn_mfma_f32_16x16x32_bf16(pA, ones, zf, 0, 0, 0);
        o0 = __builtin_amdgcn_mfma_f32_16x16x32_bf16(pA, bv0, o0, 0, 0, 0);
        o1 = __builtin_amdgcn_mfma_f32_16x16x32_bf16(pA, bv1, o1, 0, 0, 0);
        #pragma unroll
        for (int r = 0; r < 4; ++r) l[r] += lf[r];

        if (c + 1 < NC) {
            *(uint2*)&k_lds[buf ^ 1][sst] = knext;
            *(uint2*)&v_lds[buf ^ 1][sst] = vnext;
        }
        __syncthreads();
    }

    #pragma unroll
    for (int r = 0; r < 4; ++r) {
        float inv = 1.0f / l[r];
        size_t base = (size_t)(b * S + q0 + lq * 4 + r) * 256 + h * 32;
        Out[base + lm] = o0[r] * inv;
        Out[base + 16 + lm] = o1[r] * inv;
    }
}

extern "C" void kernel_launch(void* const* d_in, const int* in_sizes, int n_in,
                              void* d_out, int out_size, void* d_ws, size_t ws_size,
                              hipStream_t stream) {
    (void)in_sizes; (void)n_in; (void)out_size; (void)ws_size;
    const float* x    = (const float*)d_in[0];
    const float* ln1g = (const float*)d_in[1];
    const float* ln1b = (const float*)d_in[2];
    const float* Wq   = (const float*)d_in[3];
    const float* bq   = (const float*)d_in[4];
    const float* Wk   = (const float*)d_in[5];
    const float* bk   = (const float*)d_in[6];
    const float* Wv   = (const float*)d_in[7];
    const float* bv   = (const float*)d_in[8];
    const float* ln2g = (const float*)d_in[9];
    const float* ln2b = (const float*)d_in[10];
    const float* Wo1  = (const float*)d_in[11];
    const float* bo1  = (const float*)d_in[12];
    const float* Wo2  = (const float*)d_in[13];
    const float* bo2  = (const float*)d_in[14];
    const int*   mask = (const int*)d_in[15];
    float* out = (float*)d_out;

    const int S = SS, H = HH;
    const int T = BB * SS;                 // 8192 tokens
    const size_t NE = (size_t)T * DD;      // 2M elements
    float* ws    = (float*)d_ws;
    float* attn  = ws + 0 * NE;
    float* resid = ws + 1 * NE;
    unsigned short* q_bf   = (unsigned short*)(ws + 2 * NE);
    unsigned short* k_bf   = q_bf + NE;
    unsigned short* h_bf   = k_bf + NE;
    unsigned short* tq_bf  = h_bf + NE;    // layer-1 q out; later MLP tmp
    unsigned short* wt     = tq_bf + NE;
    unsigned short* tk_bf  = (unsigned short*)attn;       // dead before attn writes
    unsigned short* tv_bf  = tk_bf + NE;
    const int WC = 3 * DD * DD;            // 196608
    const int WM = DD * DD;
    unsigned short* wtq0 = wt;
    unsigned short* wtq1 = wt + WC;
    unsigned short* wtk0 = wt + 2 * WC;
    unsigned short* wtk1 = wt + 3 * WC;
    unsigned short* wtv0 = wt + 4 * WC;
    unsigned short* wtv1 = wt + 5 * WC;
    unsigned short* wto1 = wt + 6 * WC;
    unsigned short* wto2 = wt + 6 * WC + WM;
    unsigned short* vt_g = wt + 6 * WC + 2 * WM;  // transposed V [B*256][S]

    // fused: 8 weight transposes + LN1
    prep_kernel<<<1280 + T / 4, 256, 0, stream>>>(
        Wq, Wk, Wv, Wo1, Wo2, wt, x, ln1g, ln1b, h_bf);

    const int CG1 = (T / 32) * 3;
    const int CG  = T / 32;

    // temporal encoders, fused across q/k/v; layer 2's v-set writes Vt directly
    convf_kernel<3, true, 3, 0, false><<<CG1, 256, 0, stream>>>(
        h_bf, h_bf, h_bf, wtq0, wtk0, wtv0, bq, bk, bv,
        tq_bf, tk_bf, tv_bf, nullptr, nullptr, S);
    convf_kernel<3, false, 3, 0, true><<<CG1, 256, 0, stream>>>(
        tq_bf, tk_bf, tv_bf, wtq1, wtk1, wtv1, bq + DD, bk + DD, bv + DD,
        q_bf, k_bf, vt_g, nullptr, nullptr, S);

    // MFMA attention -> attn (fp32; overwrites tk/tv region, already consumed)
    attn_mfma_kernel<<<BB * H * (S / 64), 256, 0, stream>>>(q_bf, k_bf, vt_g, mask, attn, S, H);

    // residual + LN2 (wave-per-token)
    lnw_kernel<true><<<T / 4, 256, 0, stream>>>(x, attn, ln2g, ln2b, resid, h_bf);

    // output MLP
    convf_kernel<1, true, 1, 0, false><<<CG, 256, 0, stream>>>(
        h_bf, nullptr, nullptr, wto1, nullptr, nullptr, bo1, nullptr, nullptr,
        tq_bf, nullptr, nullptr, nullptr, nullptr, S);
    convf_kernel<1, false, 1, 2, false><<<CG, 256, 0, stream>>>(
        tq_bf, nullptr, nullptr, wto2, nullptr, nullptr, bo2, nullptr, nullptr,
        nullptr, nullptr, nullptr, resid, out, S);
}

// Round 11
// 254.801 us; speedup vs baseline: 1.4096x; 1.0341x over previous
//
#include <hip/hip_runtime.h>
#include <hip/hip_bf16.h>
#include <math.h>

// Problem constants
#define BB 4
#define SS 2048
#define DD 256
#define HH 8
#define HSZ 32

typedef __attribute__((ext_vector_type(8))) short short8;   // 8 bf16 (4 VGPRs)
typedef __attribute__((ext_vector_type(4))) float f32x4;    // MFMA C/D frag

__device__ __forceinline__ float gelu_f(float x) {
    float x3 = x * x * x;
    float z = 0.7978845608028654f * fmaf(0.044715f, x3, x);
    float e = __expf(2.0f * z);
    float t = 1.0f - 2.0f / (e + 1.0f);
    return 0.5f * x * (1.0f + t);
}

__device__ __forceinline__ unsigned short f2bf(float f) {
    unsigned int u = __float_as_uint(f);
    u = (u + 0x7fffu + ((u >> 16) & 1u)) >> 16;
    return (unsigned short)u;
}

// pack two fp32 -> two bf16 (truncation; bias cancels in softmax p/sum(p))
__device__ __forceinline__ unsigned int pack_bf16_tr(float a, float b) {
    return (__float_as_uint(a) >> 16) | (__float_as_uint(b) & 0xffff0000u);
}

// ---------------- Wave-per-token LayerNorm body (no barriers) ----------------
template<bool HASRES>
__device__ __forceinline__ void ln_wave_body(
    int t, int lane,
    const float* __restrict__ x, const float* __restrict__ addin,
    const float* __restrict__ g, const float* __restrict__ bvec,
    float* __restrict__ resid_out, unsigned short* __restrict__ oln_bf)
{
    const int base = t * DD + lane * 4;
    float4 v4 = *(const float4*)&x[base];
    if (HASRES) {
        float4 a4 = *(const float4*)&addin[base];
        v4.x += a4.x; v4.y += a4.y; v4.z += a4.z; v4.w += a4.w;
        *(float4*)&resid_out[base] = v4;
    }
    float s = (v4.x + v4.y) + (v4.z + v4.w);
    #pragma unroll
    for (int o = 1; o < 64; o <<= 1) s += __shfl_xor(s, o);
    float mean = s * (1.0f / 256.0f);
    float dx = v4.x - mean, dy = v4.y - mean, dz = v4.z - mean, dw = v4.w - mean;
    float q = (dx * dx + dy * dy) + (dz * dz + dw * dw);
    #pragma unroll
    for (int o = 1; o < 64; o <<= 1) q += __shfl_xor(q, o);
    float r = rsqrtf(q * (1.0f / 256.0f) + 1e-6f);
    const float4 g4 = *(const float4*)&g[lane * 4];
    const float4 b4 = *(const float4*)&bvec[lane * 4];
    ushort4 o4;
    o4.x = f2bf(dx * r * g4.x + b4.x);
    o4.y = f2bf(dy * r * g4.y + b4.y);
    o4.z = f2bf(dz * r * g4.z + b4.z);
    o4.w = f2bf(dw * r * g4.w + b4.w);
    *(ushort4*)&oln_bf[base] = o4;
}

// ---------------- Fused prep: weight transposes (0..1279) + LN1 (1280..3327) + maskf (3328..3335) ----------------
__global__ __launch_bounds__(256) void prep_kernel(
    const float* __restrict__ Wq, const float* __restrict__ Wk,
    const float* __restrict__ Wv, const float* __restrict__ Wo1,
    const float* __restrict__ Wo2, unsigned short* __restrict__ wt,
    const float* __restrict__ x, const float* __restrict__ ln1g,
    const float* __restrict__ ln1b, unsigned short* __restrict__ h_bf,
    const int* __restrict__ mask, float* __restrict__ maskf)
{
    if (blockIdx.x < 1280) {
        const int WCp = 3 * DD * DD;
        const int WMp = DD * DD;
        const float* src; unsigned short* dst; int R, rel;
        int i = blockIdx.x;
        if (i < 1152) {
            int seg = i / 192; rel = i % 192; R = 768;
            src = seg == 0 ? Wq : seg == 1 ? Wq + WCp : seg == 2 ? Wk :
                  seg == 3 ? Wk + WCp : seg == 4 ? Wv : Wv + WCp;
            dst = wt + (size_t)seg * WCp;
        } else {
            int j = i - 1152; int seg = j / 64; rel = j % 64; R = 256;
            src = seg == 0 ? Wo1 : Wo2;
            dst = wt + (size_t)6 * WCp + (size_t)seg * WMp;
        }
        __shared__ unsigned short t[32][33];
        const int tx = threadIdx.x & 31, ty = threadIdx.x >> 5;
        const int r0 = (rel / 8) * 32, c0 = (rel % 8) * 32;
        #pragma unroll
        for (int j = 0; j < 32; j += 8)
            t[ty + j][tx] = f2bf(src[(r0 + ty + j) * 256 + c0 + tx]);
        __syncthreads();
        #pragma unroll
        for (int j = 0; j < 32; j += 8)
            dst[(size_t)(c0 + ty + j) * R + r0 + tx] = t[tx][ty + j];
    } else if (blockIdx.x < 3328) {
        const int wv = threadIdx.x >> 6, lane = threadIdx.x & 63;
        ln_wave_body<false>((blockIdx.x - 1280) * 4 + wv, lane,
                            x, nullptr, ln1g, ln1b, nullptr, h_bf);
    } else {
        // mask -> float adds for attn (exp2 domain)
        const float M_ON  = -8.0f * 1.4426950408889634f;
        const float M_OFF = -1.442695e30f;
        int i = (blockIdx.x - 3328) * 1024 + threadIdx.x * 4;
        int4 m4 = *(const int4*)&mask[i];
        float4 f4;
        f4.x = m4.x ? M_ON : M_OFF;
        f4.y = m4.y ? M_ON : M_OFF;
        f4.z = m4.z ? M_ON : M_OFF;
        f4.w = m4.w ? M_ON : M_OFF;
        *(float4*)&maskf[i] = f4;
    }
}

// ---------------- Conv1d as bf16 MFMA implicit GEMM, 32-token tiles ----------------
// VTOUT: set 2 writes transposed V (Vt[b*256+ch][S]) via in-LDS transpose.
template<int KS, bool GELU_OUT, int NSETS, bool VTOUT>
__global__ __launch_bounds__(256) void convf_kernel(
    const unsigned short* __restrict__ in0, const unsigned short* __restrict__ in1,
    const unsigned short* __restrict__ in2,
    const unsigned short* __restrict__ W0, const unsigned short* __restrict__ W1,
    const unsigned short* __restrict__ W2,
    const float* __restrict__ bias0, const float* __restrict__ bias1,
    const float* __restrict__ bias2,
    unsigned short* __restrict__ ob0, unsigned short* __restrict__ ob1,
    unsigned short* __restrict__ ob2, int S)
{
    constexpr int TSM = 32;
    constexpr int R = TSM + KS - 1;
    constexpr int pad = (KS - 1) / 2;
    constexpr int KD = KS * 256;
    constexpr int LDW = 264;
    constexpr int TRS = 256 * 40;
    constexpr int SME = VTOUT ? (R * LDW > TRS ? R * LDW : TRS) : R * LDW;
    __shared__ __align__(16) unsigned short smem[SME];
    unsigned short (*in_lds)[LDW] = (unsigned short (*)[LDW])smem;

    int set, tile;
    if (NSETS == 3) { set = blockIdx.x % 3; tile = blockIdx.x / 3; }
    else           { set = 0;              tile = blockIdx.x; }
    const unsigned short* in   = set == 0 ? in0 : (set == 1 ? in1 : in2);
    const unsigned short* Wt   = set == 0 ? W0  : (set == 1 ? W1  : W2);
    const float* bias          = set == 0 ? bias0 : (set == 1 ? bias1 : bias2);
    unsigned short* outb       = set == 0 ? ob0 : (set == 1 ? ob1 : ob2);

    const int tid = threadIdx.x;
    const int lane = tid & 63, wv = tid >> 6;
    const int lm = lane & 15, lq = lane >> 4;
    const int tpb = S / TSM;
    const int b = tile / tpb;
    const int s0 = (tile % tpb) * TSM;

    for (int i = tid; i < R * 32; i += 256) {
        int r = i >> 5, c8 = (i & 31) << 3;
        int s = s0 + r - pad;
        int4 val = make_int4(0, 0, 0, 0);
        if (s >= 0 && s < S)
            val = *(const int4*)&in[(size_t)(b * S + s) * 256 + c8];
        *(int4*)&in_lds[r][c8] = val;
    }

    f32x4 acc[2][4];
    #pragma unroll
    for (int mt = 0; mt < 2; ++mt)
        #pragma unroll
        for (int nt = 0; nt < 4; ++nt) acc[mt][nt] = (f32x4){0.f, 0.f, 0.f, 0.f};

    const int n0 = wv * 64;
    const unsigned short* wp = Wt + (size_t)(n0 + lm) * KD + lq * 8;

    constexpr int NIT = KS * 8;
    constexpr int PD = (NIT < 3) ? NIT : 3;
    short8 bf[4][4];
    #pragma unroll
    for (int p = 0; p < PD; ++p)
        #pragma unroll
        for (int nt = 0; nt < 4; ++nt)
            bf[p][nt] = *(const short8*)(wp + p * 32 + (size_t)nt * 16 * KD);

    __syncthreads();
    #pragma unroll
    for (int it = 0; it < NIT; ++it) {
        if (it + PD < NIT) {
            #pragma unroll
            for (int nt = 0; nt < 4; ++nt)
                bf[(it + PD) & 3][nt] =
                    *(const short8*)(wp + (it + PD) * 32 + (size_t)nt * 16 * KD);
        }
        const int kk = it >> 3;
        const int icc = (it & 7) * 32 + lq * 8;
        short8 a0 = *(const short8*)&in_lds[kk + lm][icc];
        short8 a1 = *(const short8*)&in_lds[kk + 16 + lm][icc];
        #pragma unroll
        for (int nt = 0; nt < 4; ++nt) {
            acc[0][nt] = __builtin_amdgcn_mfma_f32_16x16x32_bf16(a0, bf[it & 3][nt], acc[0][nt], 0, 0, 0);
            acc[1][nt] = __builtin_amdgcn_mfma_f32_16x16x32_bf16(a1, bf[it & 3][nt], acc[1][nt], 0, 0, 0);
        }
    }

    if (VTOUT && set == 2) {
        __syncthreads();
        #pragma unroll
        for (int mt = 0; mt < 2; ++mt)
            #pragma unroll
            for (int nt = 0; nt < 4; ++nt) {
                int ch = n0 + nt * 16 + lm;
                float bv = bias[ch];
                #pragma unroll
                for (int r = 0; r < 4; ++r) {
                    int tok = mt * 16 + lq * 4 + r;
                    smem[ch * 40 + tok] = f2bf(acc[mt][nt][r] + bv);
                }
            }
        __syncthreads();
        int ch = tid;
        size_t row = ((size_t)b * 256 + ch) * S + s0;
        #pragma unroll
        for (int j = 0; j < 4; ++j) {
            uint2 lo = *(const uint2*)&smem[ch * 40 + j * 8];
            uint2 hi = *(const uint2*)&smem[ch * 40 + j * 8 + 4];
            *(int4*)&outb[row + j * 8] = make_int4(lo.x, lo.y, hi.x, hi.y);
        }
    } else {
        #pragma unroll
        for (int mt = 0; mt < 2; ++mt) {
            #pragma unroll
            for (int nt = 0; nt < 4; ++nt) {
                int o = n0 + nt * 16 + lm;
                float bv = bias[o];
                #pragma unroll
                for (int r = 0; r < 4; ++r) {
                    int t = s0 + mt * 16 + lq * 4 + r;
                    float val = acc[mt][nt][r] + bv;
                    if (GELU_OUT) val = gelu_f(val);
                    outb[(size_t)(b * S + t) * 256 + o] = f2bf(val);
                }
            }
        }
    }
}

// ---------------- Fused tail: LN2 + MLP1(gelu) + MLP2 + residual ----------------
// 16-token tiles, everything between global in (x, attn) and out stays in LDS.
__global__ __launch_bounds__(256) void tail_kernel(
    const float* __restrict__ x, const float* __restrict__ attn,
    const float* __restrict__ g2, const float* __restrict__ b2,
    const unsigned short* __restrict__ W1, const float* __restrict__ bo1,
    const unsigned short* __restrict__ W2, const float* __restrict__ bo2,
    float* __restrict__ out, int S)
{
    constexpr int LDW = 264;
    __shared__ __align__(16) unsigned short h_lds[16 * LDW];
    __shared__ __align__(16) unsigned short h2_lds[16 * LDW];
    __shared__ __align__(16) float resid_lds[16][DD];

    const int tid = threadIdx.x;
    const int lane = tid & 63, wv = tid >> 6;
    const int lm = lane & 15, lq = lane >> 4;
    const int t0 = blockIdx.x * 16;

    // LN2: wave wv -> tokens wv*4..wv*4+3 (local)
    #pragma unroll
    for (int j = 0; j < 4; ++j) {
        int t = wv * 4 + j;
        int base = (t0 + t) * DD + lane * 4;
        float4 v4 = *(const float4*)&x[base];
        float4 a4 = *(const float4*)&attn[base];
        v4.x += a4.x; v4.y += a4.y; v4.z += a4.z; v4.w += a4.w;
        *(float4*)&resid_lds[t][lane * 4] = v4;
        float s = (v4.x + v4.y) + (v4.z + v4.w);
        #pragma unroll
        for (int o = 1; o < 64; o <<= 1) s += __shfl_xor(s, o);
        float mean = s * (1.0f / 256.0f);
        float dx = v4.x - mean, dy = v4.y - mean, dz = v4.z - mean, dw = v4.w - mean;
        float q = (dx * dx + dy * dy) + (dz * dz + dw * dw);
        #pragma unroll
        for (int o = 1; o < 64; o <<= 1) q += __shfl_xor(q, o);
        float r = rsqrtf(q * (1.0f / 256.0f) + 1e-6f);
        const float4 g4 = *(const float4*)&g2[lane * 4];
        const float4 b4 = *(const float4*)&b2[lane * 4];
        ushort4 o4;
        o4.x = f2bf(dx * r * g4.x + b4.x);
        o4.y = f2bf(dy * r * g4.y + b4.y);
        o4.z = f2bf(dz * r * g4.z + b4.z);
        o4.w = f2bf(dw * r * g4.w + b4.w);
        *(ushort4*)&h_lds[t * LDW + lane * 4] = o4;
    }
    __syncthreads();

    const int n0 = wv * 64;

    // phase 1: h(16x256) @ W1 -> gelu -> h2_lds
    {
        f32x4 acc[4];
        #pragma unroll
        for (int nt = 0; nt < 4; ++nt) acc[nt] = (f32x4){0.f, 0.f, 0.f, 0.f};
        const unsigned short* wp = W1 + (size_t)(n0 + lm) * 256 + lq * 8;
        short8 bf[4][4];
        #pragma unroll
        for (int p = 0; p < 3; ++p)
            #pragma unroll
            for (int nt = 0; nt < 4; ++nt)
                bf[p][nt] = *(const short8*)(wp + p * 32 + (size_t)nt * 16 * 256);
        #pragma unroll
        for (int it = 0; it < 8; ++it) {
            if (it + 3 < 8) {
                #pragma unroll
                for (int nt = 0; nt < 4; ++nt)
                    bf[(it + 3) & 3][nt] =
                        *(const short8*)(wp + (it + 3) * 32 + (size_t)nt * 16 * 256);
            }
            short8 a0 = *(const short8*)&h_lds[lm * LDW + it * 32 + lq * 8];
            #pragma unroll
            for (int nt = 0; nt < 4; ++nt)
                acc[nt] = __builtin_amdgcn_mfma_f32_16x16x32_bf16(a0, bf[it & 3][nt], acc[nt], 0, 0, 0);
        }
        #pragma unroll
        for (int nt = 0; nt < 4; ++nt) {
            int ch = n0 + nt * 16 + lm;
            float bv = bo1[ch];
            #pragma unroll
            for (int r = 0; r < 4; ++r) {
                int tok = lq * 4 + r;
                h2_lds[tok * LDW + ch] = f2bf(gelu_f(acc[nt][r] + bv));
            }
        }
    }
    __syncthreads();

    // phase 2: h2 @ W2 + bias + resid -> out
    {
        f32x4 acc[4];
        #pragma unroll
        for (int nt = 0; nt < 4; ++nt) acc[nt] = (f32x4){0.f, 0.f, 0.f, 0.f};
        const unsigned short* wp = W2 + (size_t)(n0 + lm) * 256 + lq * 8;
        short8 bf[4][4];
        #pragma unroll
        for (int p = 0; p < 3; ++p)
            #pragma unroll
            for (int nt = 0; nt < 4; ++nt)
                bf[p][nt] = *(const short8*)(wp + p * 32 + (size_t)nt * 16 * 256);
        #pragma unroll
        for (int it = 0; it < 8; ++it) {
            if (it + 3 < 8) {
                #pragma unroll
                for (int nt = 0; nt < 4; ++nt)
                    bf[(it + 3) & 3][nt] =
                        *(const short8*)(wp + (it + 3) * 32 + (size_t)nt * 16 * 256);
            }
            short8 a0 = *(const short8*)&h2_lds[lm * LDW + it * 32 + lq * 8];
            #pragma unroll
            for (int nt = 0; nt < 4; ++nt)
                acc[nt] = __builtin_amdgcn_mfma_f32_16x16x32_bf16(a0, bf[it & 3][nt], acc[nt], 0, 0, 0);
        }
        #pragma unroll
        for (int nt = 0; nt < 4; ++nt) {
            int ch = n0 + nt * 16 + lm;
            float bv = bo2[ch];
            #pragma unroll
            for (int r = 0; r < 4; ++r) {
                int tok = lq * 4 + r;
                out[(size_t)(t0 + tok) * DD + ch] = acc[nt][r] + bv + resid_lds[tok][ch];
            }
        }
    }
}

// ---------------- MFMA flash attention v4 (float mask-adds; otherwise round-7 verified) ----------------
__global__ __launch_bounds__(256) void attn_mfma_kernel(
    const unsigned short* __restrict__ Qb, const unsigned short* __restrict__ Kb,
    const unsigned short* __restrict__ Vt, const float* __restrict__ maskf,
    float* __restrict__ Out, int S, int H)
{
    constexpr int LDK = 40;
    constexpr int LDP = 40;
    __shared__ __align__(16) unsigned short k_lds[2][32 * LDK];
    __shared__ __align__(16) unsigned short v_lds[2][32 * LDK];
    __shared__ __align__(16) unsigned short p_lds[4][16 * LDP];

    const int qtiles = S / 64;
    const int qt = (blockIdx.x % qtiles) * 64;
    const int bh = blockIdx.x / qtiles;
    const int b = bh / H, h = bh % H;
    const int tid = threadIdx.x;
    const int lane = tid & 63, wv = tid >> 6;
    const int lm = lane & 15, lq = lane >> 4;
    const int q0 = qt + wv * 16;

    short8 qfrag = *(const short8*)&Qb[(size_t)(b * S + q0 + lm) * 256 + h * 32 + lq * 8];

    short8 ones;
    #pragma unroll
    for (int j = 0; j < 8; ++j) ones[j] = (short)0x3F80;  // bf16 1.0

    f32x4 o0 = {0.f, 0.f, 0.f, 0.f}, o1 = {0.f, 0.f, 0.f, 0.f};
    const f32x4 zf = {0.f, 0.f, 0.f, 0.f};
    float l[4] = {0.f, 0.f, 0.f, 0.f};

    const float scale2 = 0.17677669529663687f * 1.4426950408889634f;

    const int srow = tid >> 3, soff = (tid & 7) * 4;
    const unsigned short* kgp = Kb + (size_t)(b * S + srow) * 256 + h * 32 + soff;
    const unsigned short* vgp = Vt + (size_t)(bh * 32 + srow) * S + soff;
    const int sst = srow * LDK + soff;

    const int f0 = lm * LDK + lq * 8;
    const int f1 = (16 + lm) * LDK + lq * 8;
    const float* mp0 = maskf + b * S + lq * 4;
    const float* mp1 = mp0 + 16;

    unsigned short* pw = p_lds[wv];
    const int pst = lm * LDP + lq * 4;
    const int prd = lm * LDP + lq * 8;

    const int NC = S / 32;

    {
        uint2 kv = *(const uint2*)kgp;
        uint2 vv = *(const uint2*)vgp;
        *(uint2*)&k_lds[0][sst] = kv;
        *(uint2*)&v_lds[0][sst] = vv;
    }
    __syncthreads();

    for (int c = 0; c < NC; ++c) {
        const int buf = c & 1;

        uint2 knext, vnext;
        if (c + 1 < NC) {
            knext = *(const uint2*)(kgp + (size_t)(c + 1) * 32 * 256);
            vnext = *(const uint2*)(vgp + (c + 1) * 32);
        }

        short8 kf0 = *(const short8*)&k_lds[buf][f0];
        short8 kf1 = *(const short8*)&k_lds[buf][f1];
        f32x4 s0 = __builtin_amdgcn_mfma_f32_16x16x32_bf16(kf0, qfrag, zf, 0, 0, 0);
        f32x4 s1 = __builtin_amdgcn_mfma_f32_16x16x32_bf16(kf1, qfrag, zf, 0, 0, 0);

        float4 mf0 = *(const float4*)(mp0 + c * 32);
        float4 mf1 = *(const float4*)(mp1 + c * 32);

        float p[8];
        p[0] = exp2f(fmaf(s0[0], scale2, mf0.x));
        p[1] = exp2f(fmaf(s0[1], scale2, mf0.y));
        p[2] = exp2f(fmaf(s0[2], scale2, mf0.z));
        p[3] = exp2f(fmaf(s0[3], scale2, mf0.w));
        p[4] = exp2f(fmaf(s1[0], scale2, mf1.x));
        p[5] = exp2f(fmaf(s1[1], scale2, mf1.y));
        p[6] = exp2f(fmaf(s1[2], scale2, mf1.z));
        p[7] = exp2f(fmaf(s1[3], scale2, mf1.w));

        uint2 w0, w1;
        w0.x = pack_bf16_tr(p[0], p[1]); w0.y = pack_bf16_tr(p[2], p[3]);
        w1.x = pack_bf16_tr(p[4], p[5]); w1.y = pack_bf16_tr(p[6], p[7]);
        *(uint2*)&pw[pst] = w0;
        *(uint2*)&pw[pst + 16] = w1;

        short8 pA = *(const short8*)&pw[prd];

        short8 bv0 = *(const short8*)&v_lds[buf][f0];
        short8 bv1 = *(const short8*)&v_lds[buf][f1];
        f32x4 lf = __builtin_amdgcn_mfma_f32_16x16x32_bf16(pA, ones, zf, 0, 0, 0);
        o0 = __builtin_amdgcn_mfma_f32_16x16x32_bf16(pA, bv0, o0, 0, 0, 0);
        o1 = __builtin_amdgcn_mfma_f32_16x16x32_bf16(pA, bv1, o1, 0, 0, 0);
        #pragma unroll
        for (int r = 0; r < 4; ++r) l[r] += lf[r];

        if (c + 1 < NC) {
            *(uint2*)&k_lds[buf ^ 1][sst] = knext;
            *(uint2*)&v_lds[buf ^ 1][sst] = vnext;
        }
        __syncthreads();
    }

    #pragma unroll
    for (int r = 0; r < 4; ++r) {
        float inv = 1.0f / l[r];
        size_t base = (size_t)(b * S + q0 + lq * 4 + r) * 256 + h * 32;
        Out[base + lm] = o0[r] * inv;
        Out[base + 16 + lm] = o1[r] * inv;
    }
}

extern "C" void kernel_launch(void* const* d_in, const int* in_sizes, int n_in,
                              void* d_out, int out_size, void* d_ws, size_t ws_size,
                              hipStream_t stream) {
    (void)in_sizes; (void)n_in; (void)out_size; (void)ws_size;
    const float* x    = (const float*)d_in[0];
    const float* ln1g = (const float*)d_in[1];
    const float* ln1b = (const float*)d_in[2];
    const float* Wq   = (const float*)d_in[3];
    const float* bq   = (const float*)d_in[4];
    const float* Wk   = (const float*)d_in[5];
    const float* bk   = (const float*)d_in[6];
    const float* Wv   = (const float*)d_in[7];
    const float* bv   = (const float*)d_in[8];
    const float* ln2g = (const float*)d_in[9];
    const float* ln2b = (const float*)d_in[10];
    const float* Wo1  = (const float*)d_in[11];
    const float* bo1  = (const float*)d_in[12];
    const float* Wo2  = (const float*)d_in[13];
    const float* bo2  = (const float*)d_in[14];
    const int*   mask = (const int*)d_in[15];
    float* out = (float*)d_out;

    const int S = SS, H = HH;
    const int T = BB * SS;                 // 8192 tokens
    const size_t NE = (size_t)T * DD;      // 2M elements
    float* ws    = (float*)d_ws;
    float* attn  = ws + 0 * NE;
    float* maskf = ws + 1 * NE;            // 8192 floats used
    unsigned short* q_bf   = (unsigned short*)(ws + 2 * NE);
    unsigned short* k_bf   = q_bf + NE;
    unsigned short* h_bf   = k_bf + NE;
    unsigned short* tq_bf  = h_bf + NE;    // conv layer-1 q out
    unsigned short* wt     = tq_bf + NE;
    unsigned short* tk_bf  = (unsigned short*)attn;       // dead before attn writes
    unsigned short* tv_bf  = tk_bf + NE;
    const int WC = 3 * DD * DD;            // 196608
    const int WM = DD * DD;
    unsigned short* wtq0 = wt;
    unsigned short* wtq1 = wt + WC;
    unsigned short* wtk0 = wt + 2 * WC;
    unsigned short* wtk1 = wt + 3 * WC;
    unsigned short* wtv0 = wt + 4 * WC;
    unsigned short* wtv1 = wt + 5 * WC;
    unsigned short* wto1 = wt + 6 * WC;
    unsigned short* wto2 = wt + 6 * WC + WM;
    unsigned short* vt_g = wt + 6 * WC + 2 * WM;  // transposed V [B*256][S]

    // fused: 8 weight transposes + LN1 + mask->float
    prep_kernel<<<1280 + T / 4 + 8, 256, 0, stream>>>(
        Wq, Wk, Wv, Wo1, Wo2, wt, x, ln1g, ln1b, h_bf, mask, maskf);

    const int CG1 = (T / 32) * 3;

    // temporal encoders, fused across q/k/v; layer 2's v-set writes Vt directly
    convf_kernel<3, true, 3, false><<<CG1, 256, 0, stream>>>(
        h_bf, h_bf, h_bf, wtq0, wtk0, wtv0, bq, bk, bv,
        tq_bf, tk_bf, tv_bf, S);
    convf_kernel<3, false, 3, true><<<CG1, 256, 0, stream>>>(
        tq_bf, tk_bf, tv_bf, wtq1, wtk1, wtv1, bq + DD, bk + DD, bv + DD,
        q_bf, k_bf, vt_g, S);

    // MFMA attention -> attn (fp32; overwrites tk/tv region, already consumed)
    attn_mfma_kernel<<<BB * H * (S / 64), 256, 0, stream>>>(q_bf, k_bf, vt_g, maskf, attn, S, H);

    // fused tail: LN2 + MLP1 + GELU + MLP2 + residual -> out
    tail_kernel<<<T / 16, 256, 0, stream>>>(
        x, attn, ln2g, ln2b, wto1, bo1, wto2, bo2, out, S);
}

// Round 12
// 244.276 us; speedup vs baseline: 1.4703x; 1.0431x over previous
//
#include <hip/hip_runtime.h>
#include <hip/hip_bf16.h>
#include <math.h>

// Problem constants
#define BB 4
#define SS 2048
#define DD 256
#define HH 8
#define HSZ 32

typedef __attribute__((ext_vector_type(8))) short short8;   // 8 bf16 (4 VGPRs)
typedef __attribute__((ext_vector_type(4))) float f32x4;    // MFMA C/D frag

__device__ __forceinline__ float gelu_f(float x) {
    float x3 = x * x * x;
    float z = 0.7978845608028654f * fmaf(0.044715f, x3, x);
    float e = __expf(2.0f * z);
    float t = 1.0f - 2.0f / (e + 1.0f);
    return 0.5f * x * (1.0f + t);
}

__device__ __forceinline__ unsigned short f2bf(float f) {
    unsigned int u = __float_as_uint(f);
    u = (u + 0x7fffu + ((u >> 16) & 1u)) >> 16;
    return (unsigned short)u;
}

// pack two fp32 -> two bf16 (truncation; bias cancels in softmax p/sum(p))
__device__ __forceinline__ unsigned int pack_bf16_tr(float a, float b) {
    return (__float_as_uint(a) >> 16) | (__float_as_uint(b) & 0xffff0000u);
}

// ---------------- Wave-per-token LayerNorm body (no barriers) ----------------
template<bool HASRES>
__device__ __forceinline__ void ln_wave_body(
    int t, int lane,
    const float* __restrict__ x, const float* __restrict__ addin,
    const float* __restrict__ g, const float* __restrict__ bvec,
    float* __restrict__ resid_out, unsigned short* __restrict__ oln_bf)
{
    const int base = t * DD + lane * 4;
    float4 v4 = *(const float4*)&x[base];
    if (HASRES) {
        float4 a4 = *(const float4*)&addin[base];
        v4.x += a4.x; v4.y += a4.y; v4.z += a4.z; v4.w += a4.w;
        *(float4*)&resid_out[base] = v4;
    }
    float s = (v4.x + v4.y) + (v4.z + v4.w);
    #pragma unroll
    for (int o = 1; o < 64; o <<= 1) s += __shfl_xor(s, o);
    float mean = s * (1.0f / 256.0f);
    float dx = v4.x - mean, dy = v4.y - mean, dz = v4.z - mean, dw = v4.w - mean;
    float q = (dx * dx + dy * dy) + (dz * dz + dw * dw);
    #pragma unroll
    for (int o = 1; o < 64; o <<= 1) q += __shfl_xor(q, o);
    float r = rsqrtf(q * (1.0f / 256.0f) + 1e-6f);
    const float4 g4 = *(const float4*)&g[lane * 4];
    const float4 b4 = *(const float4*)&bvec[lane * 4];
    ushort4 o4;
    o4.x = f2bf(dx * r * g4.x + b4.x);
    o4.y = f2bf(dy * r * g4.y + b4.y);
    o4.z = f2bf(dz * r * g4.z + b4.z);
    o4.w = f2bf(dw * r * g4.w + b4.w);
    *(ushort4*)&oln_bf[base] = o4;
}

// ---------------- Fused prep: weight transposes (0..1279) + LN1 (1280..3327) + maskf (3328..3335) ----------------
__global__ __launch_bounds__(256) void prep_kernel(
    const float* __restrict__ Wq, const float* __restrict__ Wk,
    const float* __restrict__ Wv, const float* __restrict__ Wo1,
    const float* __restrict__ Wo2, unsigned short* __restrict__ wt,
    const float* __restrict__ x, const float* __restrict__ ln1g,
    const float* __restrict__ ln1b, unsigned short* __restrict__ h_bf,
    const int* __restrict__ mask, float* __restrict__ maskf)
{
    if (blockIdx.x < 1280) {
        const int WCp = 3 * DD * DD;
        const int WMp = DD * DD;
        const float* src; unsigned short* dst; int R, rel;
        int i = blockIdx.x;
        if (i < 1152) {
            int seg = i / 192; rel = i % 192; R = 768;
            src = seg == 0 ? Wq : seg == 1 ? Wq + WCp : seg == 2 ? Wk :
                  seg == 3 ? Wk + WCp : seg == 4 ? Wv : Wv + WCp;
            dst = wt + (size_t)seg * WCp;
        } else {
            int j = i - 1152; int seg = j / 64; rel = j % 64; R = 256;
            src = seg == 0 ? Wo1 : Wo2;
            dst = wt + (size_t)6 * WCp + (size_t)seg * WMp;
        }
        __shared__ unsigned short t[32][33];
        const int tx = threadIdx.x & 31, ty = threadIdx.x >> 5;
        const int r0 = (rel / 8) * 32, c0 = (rel % 8) * 32;
        #pragma unroll
        for (int j = 0; j < 32; j += 8)
            t[ty + j][tx] = f2bf(src[(r0 + ty + j) * 256 + c0 + tx]);
        __syncthreads();
        #pragma unroll
        for (int j = 0; j < 32; j += 8)
            dst[(size_t)(c0 + ty + j) * R + r0 + tx] = t[tx][ty + j];
    } else if (blockIdx.x < 3328) {
        const int wv = threadIdx.x >> 6, lane = threadIdx.x & 63;
        ln_wave_body<false>((blockIdx.x - 1280) * 4 + wv, lane,
                            x, nullptr, ln1g, ln1b, nullptr, h_bf);
    } else {
        const float M_ON  = -8.0f * 1.4426950408889634f;
        const float M_OFF = -1.442695e30f;
        int i = (blockIdx.x - 3328) * 1024 + threadIdx.x * 4;
        int4 m4 = *(const int4*)&mask[i];
        float4 f4;
        f4.x = m4.x ? M_ON : M_OFF;
        f4.y = m4.y ? M_ON : M_OFF;
        f4.z = m4.z ? M_ON : M_OFF;
        f4.w = m4.w ? M_ON : M_OFF;
        *(float4*)&maskf[i] = f4;
    }
}

// ---------------- Fused dual-layer conv3 (per q/k/v set), intermediate in LDS ----------------
// Block = one (set, 32-token tile). Layer-1 computed for 34 rows (+halo,
// 3 M-tiles, rows >=34 discarded; staging zero-filled so no garbage NaNs),
// gelu -> inter (LDS), layer-2 for 32 rows. Set 2 writes transposed V.
__global__ __launch_bounds__(256) void convdual_kernel(
    const unsigned short* __restrict__ in,
    const unsigned short* __restrict__ W0a, const unsigned short* __restrict__ W0b,
    const unsigned short* __restrict__ W0c,
    const unsigned short* __restrict__ W1a, const unsigned short* __restrict__ W1b,
    const unsigned short* __restrict__ W1c,
    const float* __restrict__ ba, const float* __restrict__ bb,
    const float* __restrict__ bc,
    unsigned short* __restrict__ oq, unsigned short* __restrict__ ok,
    unsigned short* __restrict__ ovt, int S)
{
    constexpr int LDW = 264;
    // stage: rows 0..35 = h[s0-2 .. s0+33], rows 36..49 zero (layer-1 m-tile-2 overreach)
    __shared__ __align__(16) unsigned short stage[50 * LDW];   // 26.4 KB; reused for V transpose
    __shared__ __align__(16) unsigned short inter[34 * LDW];   // 18 KB

    const int set = blockIdx.x % 3;
    const int tile = blockIdx.x / 3;
    const unsigned short* W0 = set == 0 ? W0a : (set == 1 ? W0b : W0c);
    const unsigned short* W1 = set == 0 ? W1a : (set == 1 ? W1b : W1c);
    const float* bias         = set == 0 ? ba  : (set == 1 ? bb  : bc);

    const int tid = threadIdx.x;
    const int lane = tid & 63, wv = tid >> 6;
    const int lm = lane & 15, lq = lane >> 4;
    const int tpb = S / 32;
    const int b = tile / tpb;
    const int s0 = (tile % tpb) * 32;

    for (int i = tid; i < 36 * 32; i += 256) {
        int r = i >> 5, c8 = (i & 31) << 3;
        int s = s0 + r - 2;
        int4 val = make_int4(0, 0, 0, 0);
        if (s >= 0 && s < S)
            val = *(const int4*)&in[(size_t)(b * S + s) * 256 + c8];
        *(int4*)&stage[r * LDW + c8] = val;
    }
    for (int i = tid; i < 14 * 32; i += 256) {
        int r = 36 + (i >> 5), c8 = (i & 31) << 3;
        *(int4*)&stage[r * LDW + c8] = make_int4(0, 0, 0, 0);
    }

    const int n0 = wv * 64;

    // ---- layer 1: out1[j] (j=0..33, token s0-1+j) = conv3(h)[.], gelu ----
    {
        f32x4 acc[3][4];
        #pragma unroll
        for (int mt = 0; mt < 3; ++mt)
            #pragma unroll
            for (int nt = 0; nt < 4; ++nt) acc[mt][nt] = (f32x4){0.f, 0.f, 0.f, 0.f};

        const unsigned short* wp = W0 + (size_t)(n0 + lm) * 768 + lq * 8;
        short8 bf[4][4];
        #pragma unroll
        for (int p = 0; p < 3; ++p)
            #pragma unroll
            for (int nt = 0; nt < 4; ++nt)
                bf[p][nt] = *(const short8*)(wp + p * 32 + (size_t)nt * 16 * 768);

        __syncthreads();
        #pragma unroll
        for (int it = 0; it < 24; ++it) {
            if (it + 3 < 24) {
                #pragma unroll
                for (int nt = 0; nt < 4; ++nt)
                    bf[(it + 3) & 3][nt] =
                        *(const short8*)(wp + (it + 3) * 32 + (size_t)nt * 16 * 768);
            }
            const int kk = it >> 3;
            const int icc = (it & 7) * 32 + lq * 8;
            short8 a0 = *(const short8*)&stage[(kk + lm) * LDW + icc];
            short8 a1 = *(const short8*)&stage[(kk + 16 + lm) * LDW + icc];
            short8 a2 = *(const short8*)&stage[(kk + 32 + lm) * LDW + icc];
            #pragma unroll
            for (int nt = 0; nt < 4; ++nt) {
                acc[0][nt] = __builtin_amdgcn_mfma_f32_16x16x32_bf16(a0, bf[it & 3][nt], acc[0][nt], 0, 0, 0);
                acc[1][nt] = __builtin_amdgcn_mfma_f32_16x16x32_bf16(a1, bf[it & 3][nt], acc[1][nt], 0, 0, 0);
                acc[2][nt] = __builtin_amdgcn_mfma_f32_16x16x32_bf16(a2, bf[it & 3][nt], acc[2][nt], 0, 0, 0);
            }
        }

        #pragma unroll
        for (int mt = 0; mt < 3; ++mt)
            #pragma unroll
            for (int nt = 0; nt < 4; ++nt) {
                int ch = n0 + nt * 16 + lm;
                float bv = bias[ch];
                #pragma unroll
                for (int r = 0; r < 4; ++r) {
                    int j = mt * 16 + lq * 4 + r;
                    if (j < 34)
                        inter[j * LDW + ch] = f2bf(gelu_f(acc[mt][nt][r] + bv));
                }
            }
    }
    __syncthreads();

    // ---- layer 2: out[m] (m=0..31, token s0+m) = conv3(out1)[.] ----
    f32x4 acc2[2][4];
    #pragma unroll
    for (int mt = 0; mt < 2; ++mt)
        #pragma unroll
        for (int nt = 0; nt < 4; ++nt) acc2[mt][nt] = (f32x4){0.f, 0.f, 0.f, 0.f};
    {
        const unsigned short* wp = W1 + (size_t)(n0 + lm) * 768 + lq * 8;
        short8 bf[4][4];
        #pragma unroll
        for (int p = 0; p < 3; ++p)
            #pragma unroll
            for (int nt = 0; nt < 4; ++nt)
                bf[p][nt] = *(const short8*)(wp + p * 32 + (size_t)nt * 16 * 768);

        #pragma unroll
        for (int it = 0; it < 24; ++it) {
            if (it + 3 < 24) {
                #pragma unroll
                for (int nt = 0; nt < 4; ++nt)
                    bf[(it + 3) & 3][nt] =
                        *(const short8*)(wp + (it + 3) * 32 + (size_t)nt * 16 * 768);
            }
            const int kk = it >> 3;
            const int icc = (it & 7) * 32 + lq * 8;
            short8 a0 = *(const short8*)&inter[(kk + lm) * LDW + icc];
            short8 a1 = *(const short8*)&inter[(kk + 16 + lm) * LDW + icc];
            #pragma unroll
            for (int nt = 0; nt < 4; ++nt) {
                acc2[0][nt] = __builtin_amdgcn_mfma_f32_16x16x32_bf16(a0, bf[it & 3][nt], acc2[0][nt], 0, 0, 0);
                acc2[1][nt] = __builtin_amdgcn_mfma_f32_16x16x32_bf16(a1, bf[it & 3][nt], acc2[1][nt], 0, 0, 0);
            }
        }
    }

    if (set < 2) {
        unsigned short* outb = set == 0 ? oq : ok;
        #pragma unroll
        for (int mt = 0; mt < 2; ++mt)
            #pragma unroll
            for (int nt = 0; nt < 4; ++nt) {
                int o = n0 + nt * 16 + lm;
                float bv = bias[256 + o];
                #pragma unroll
                for (int r = 0; r < 4; ++r) {
                    int t = s0 + mt * 16 + lq * 4 + r;
                    outb[(size_t)(b * S + t) * 256 + o] = f2bf(acc2[mt][nt][r] + bv);
                }
            }
    } else {
        // V: transpose epilogue -> Vt[b*256+ch][S]
        __syncthreads();
        #pragma unroll
        for (int mt = 0; mt < 2; ++mt)
            #pragma unroll
            for (int nt = 0; nt < 4; ++nt) {
                int ch = n0 + nt * 16 + lm;
                float bv = bias[256 + ch];
                #pragma unroll
                for (int r = 0; r < 4; ++r) {
                    int tok = mt * 16 + lq * 4 + r;
                    stage[ch * 40 + tok] = f2bf(acc2[mt][nt][r] + bv);
                }
            }
        __syncthreads();
        int ch = tid;
        size_t row = ((size_t)b * 256 + ch) * S + s0;
        #pragma unroll
        for (int j = 0; j < 4; ++j) {
            uint2 lo = *(const uint2*)&stage[ch * 40 + j * 8];
            uint2 hi = *(const uint2*)&stage[ch * 40 + j * 8 + 4];
            *(int4*)&ovt[row + j * 8] = make_int4(lo.x, lo.y, hi.x, hi.y);
        }
    }
}

// ---------------- Fused tail: LN2 + MLP1(gelu) + MLP2 + residual ----------------
__global__ __launch_bounds__(256) void tail_kernel(
    const float* __restrict__ x, const float* __restrict__ attn,
    const float* __restrict__ g2, const float* __restrict__ b2,
    const unsigned short* __restrict__ W1, const float* __restrict__ bo1,
    const unsigned short* __restrict__ W2, const float* __restrict__ bo2,
    float* __restrict__ out, int S)
{
    constexpr int LDW = 264;
    __shared__ __align__(16) unsigned short h_lds[16 * LDW];
    __shared__ __align__(16) unsigned short h2_lds[16 * LDW];
    __shared__ __align__(16) float resid_lds[16][DD];

    const int tid = threadIdx.x;
    const int lane = tid & 63, wv = tid >> 6;
    const int lm = lane & 15, lq = lane >> 4;
    const int t0 = blockIdx.x * 16;

    #pragma unroll
    for (int j = 0; j < 4; ++j) {
        int t = wv * 4 + j;
        int base = (t0 + t) * DD + lane * 4;
        float4 v4 = *(const float4*)&x[base];
        float4 a4 = *(const float4*)&attn[base];
        v4.x += a4.x; v4.y += a4.y; v4.z += a4.z; v4.w += a4.w;
        *(float4*)&resid_lds[t][lane * 4] = v4;
        float s = (v4.x + v4.y) + (v4.z + v4.w);
        #pragma unroll
        for (int o = 1; o < 64; o <<= 1) s += __shfl_xor(s, o);
        float mean = s * (1.0f / 256.0f);
        float dx = v4.x - mean, dy = v4.y - mean, dz = v4.z - mean, dw = v4.w - mean;
        float q = (dx * dx + dy * dy) + (dz * dz + dw * dw);
        #pragma unroll
        for (int o = 1; o < 64; o <<= 1) q += __shfl_xor(q, o);
        float r = rsqrtf(q * (1.0f / 256.0f) + 1e-6f);
        const float4 g4 = *(const float4*)&g2[lane * 4];
        const float4 b4 = *(const float4*)&b2[lane * 4];
        ushort4 o4;
        o4.x = f2bf(dx * r * g4.x + b4.x);
        o4.y = f2bf(dy * r * g4.y + b4.y);
        o4.z = f2bf(dz * r * g4.z + b4.z);
        o4.w = f2bf(dw * r * g4.w + b4.w);
        *(ushort4*)&h_lds[t * LDW + lane * 4] = o4;
    }
    __syncthreads();

    const int n0 = wv * 64;

    {
        f32x4 acc[4];
        #pragma unroll
        for (int nt = 0; nt < 4; ++nt) acc[nt] = (f32x4){0.f, 0.f, 0.f, 0.f};
        const unsigned short* wp = W1 + (size_t)(n0 + lm) * 256 + lq * 8;
        short8 bf[4][4];
        #pragma unroll
        for (int p = 0; p < 3; ++p)
            #pragma unroll
            for (int nt = 0; nt < 4; ++nt)
                bf[p][nt] = *(const short8*)(wp + p * 32 + (size_t)nt * 16 * 256);
        #pragma unroll
        for (int it = 0; it < 8; ++it) {
            if (it + 3 < 8) {
                #pragma unroll
                for (int nt = 0; nt < 4; ++nt)
                    bf[(it + 3) & 3][nt] =
                        *(const short8*)(wp + (it + 3) * 32 + (size_t)nt * 16 * 256);
            }
            short8 a0 = *(const short8*)&h_lds[lm * LDW + it * 32 + lq * 8];
            #pragma unroll
            for (int nt = 0; nt < 4; ++nt)
                acc[nt] = __builtin_amdgcn_mfma_f32_16x16x32_bf16(a0, bf[it & 3][nt], acc[nt], 0, 0, 0);
        }
        #pragma unroll
        for (int nt = 0; nt < 4; ++nt) {
            int ch = n0 + nt * 16 + lm;
            float bv = bo1[ch];
            #pragma unroll
            for (int r = 0; r < 4; ++r) {
                int tok = lq * 4 + r;
                h2_lds[tok * LDW + ch] = f2bf(gelu_f(acc[nt][r] + bv));
            }
        }
    }
    __syncthreads();

    {
        f32x4 acc[4];
        #pragma unroll
        for (int nt = 0; nt < 4; ++nt) acc[nt] = (f32x4){0.f, 0.f, 0.f, 0.f};
        const unsigned short* wp = W2 + (size_t)(n0 + lm) * 256 + lq * 8;
        short8 bf[4][4];
        #pragma unroll
        for (int p = 0; p < 3; ++p)
            #pragma unroll
            for (int nt = 0; nt < 4; ++nt)
                bf[p][nt] = *(const short8*)(wp + p * 32 + (size_t)nt * 16 * 256);
        #pragma unroll
        for (int it = 0; it < 8; ++it) {
            if (it + 3 < 8) {
                #pragma unroll
                for (int nt = 0; nt < 4; ++nt)
                    bf[(it + 3) & 3][nt] =
                        *(const short8*)(wp + (it + 3) * 32 + (size_t)nt * 16 * 256);
            }
            short8 a0 = *(const short8*)&h2_lds[lm * LDW + it * 32 + lq * 8];
            #pragma unroll
            for (int nt = 0; nt < 4; ++nt)
                acc[nt] = __builtin_amdgcn_mfma_f32_16x16x32_bf16(a0, bf[it & 3][nt], acc[nt], 0, 0, 0);
        }
        #pragma unroll
        for (int nt = 0; nt < 4; ++nt) {
            int ch = n0 + nt * 16 + lm;
            float bv = bo2[ch];
            #pragma unroll
            for (int r = 0; r < 4; ++r) {
                int tok = lq * 4 + r;
                out[(size_t)(t0 + tok) * DD + ch] = acc[nt][r] + bv + resid_lds[tok][ch];
            }
        }
    }
}

// ---------------- MFMA flash attention v5: XCD-swizzled block mapping ----------------
// All 32 q-tile blocks of one (b,h) land on one XCD (round-robin assumption,
// perf-only): bh from i&31 pattern, qtile from i>>5.
__global__ __launch_bounds__(256) void attn_mfma_kernel(
    const unsigned short* __restrict__ Qb, const unsigned short* __restrict__ Kb,
    const unsigned short* __restrict__ Vt, const float* __restrict__ maskf,
    float* __restrict__ Out, int S, int H)
{
    constexpr int LDK = 40;
    constexpr int LDP = 40;
    __shared__ __align__(16) unsigned short k_lds[2][32 * LDK];
    __shared__ __align__(16) unsigned short v_lds[2][32 * LDK];
    __shared__ __align__(16) unsigned short p_lds[4][16 * LDP];

    const int bh = ((blockIdx.x & 7) << 2) | ((blockIdx.x >> 3) & 3);
    const int qt = (blockIdx.x >> 5) * 64;
    const int b = bh / H, h = bh % H;
    const int tid = threadIdx.x;
    const int lane = tid & 63, wv = tid >> 6;
    const int lm = lane & 15, lq = lane >> 4;
    const int q0 = qt + wv * 16;

    short8 qfrag = *(const short8*)&Qb[(size_t)(b * S + q0 + lm) * 256 + h * 32 + lq * 8];

    short8 ones;
    #pragma unroll
    for (int j = 0; j < 8; ++j) ones[j] = (short)0x3F80;  // bf16 1.0

    f32x4 o0 = {0.f, 0.f, 0.f, 0.f}, o1 = {0.f, 0.f, 0.f, 0.f};
    const f32x4 zf = {0.f, 0.f, 0.f, 0.f};
    float l[4] = {0.f, 0.f, 0.f, 0.f};

    const float scale2 = 0.17677669529663687f * 1.4426950408889634f;

    const int srow = tid >> 3, soff = (tid & 7) * 4;
    const unsigned short* kgp = Kb + (size_t)(b * S + srow) * 256 + h * 32 + soff;
    const unsigned short* vgp = Vt + (size_t)(bh * 32 + srow) * S + soff;
    const int sst = srow * LDK + soff;

    const int f0 = lm * LDK + lq * 8;
    const int f1 = (16 + lm) * LDK + lq * 8;
    const float* mp0 = maskf + b * S + lq * 4;
    const float* mp1 = mp0 + 16;

    unsigned short* pw = p_lds[wv];
    const int pst = lm * LDP + lq * 4;
    const int prd = lm * LDP + lq * 8;

    const int NC = S / 32;

    {
        uint2 kv = *(const uint2*)kgp;
        uint2 vv = *(const uint2*)vgp;
        *(uint2*)&k_lds[0][sst] = kv;
        *(uint2*)&v_lds[0][sst] = vv;
    }
    __syncthreads();

    for (int c = 0; c < NC; ++c) {
        const int buf = c & 1;

        uint2 knext, vnext;
        if (c + 1 < NC) {
            knext = *(const uint2*)(kgp + (size_t)(c + 1) * 32 * 256);
            vnext = *(const uint2*)(vgp + (c + 1) * 32);
        }

        short8 kf0 = *(const short8*)&k_lds[buf][f0];
        short8 kf1 = *(const short8*)&k_lds[buf][f1];
        f32x4 s0 = __builtin_amdgcn_mfma_f32_16x16x32_bf16(kf0, qfrag, zf, 0, 0, 0);
        f32x4 s1 = __builtin_amdgcn_mfma_f32_16x16x32_bf16(kf1, qfrag, zf, 0, 0, 0);

        float4 mf0 = *(const float4*)(mp0 + c * 32);
        float4 mf1 = *(const float4*)(mp1 + c * 32);

        float p[8];
        p[0] = exp2f(fmaf(s0[0], scale2, mf0.x));
        p[1] = exp2f(fmaf(s0[1], scale2, mf0.y));
        p[2] = exp2f(fmaf(s0[2], scale2, mf0.z));
        p[3] = exp2f(fmaf(s0[3], scale2, mf0.w));
        p[4] = exp2f(fmaf(s1[0], scale2, mf1.x));
        p[5] = exp2f(fmaf(s1[1], scale2, mf1.y));
        p[6] = exp2f(fmaf(s1[2], scale2, mf1.z));
        p[7] = exp2f(fmaf(s1[3], scale2, mf1.w));

        uint2 w0, w1;
        w0.x = pack_bf16_tr(p[0], p[1]); w0.y = pack_bf16_tr(p[2], p[3]);
        w1.x = pack_bf16_tr(p[4], p[5]); w1.y = pack_bf16_tr(p[6], p[7]);
        *(uint2*)&pw[pst] = w0;
        *(uint2*)&pw[pst + 16] = w1;

        short8 pA = *(const short8*)&pw[prd];

        short8 bv0 = *(const short8*)&v_lds[buf][f0];
        short8 bv1 = *(const short8*)&v_lds[buf][f1];
        f32x4 lf = __builtin_amdgcn_mfma_f32_16x16x32_bf16(pA, ones, zf, 0, 0, 0);
        o0 = __builtin_amdgcn_mfma_f32_16x16x32_bf16(pA, bv0, o0, 0, 0, 0);
        o1 = __builtin_amdgcn_mfma_f32_16x16x32_bf16(pA, bv1, o1, 0, 0, 0);
        #pragma unroll
        for (int r = 0; r < 4; ++r) l[r] += lf[r];

        if (c + 1 < NC) {
            *(uint2*)&k_lds[buf ^ 1][sst] = knext;
            *(uint2*)&v_lds[buf ^ 1][sst] = vnext;
        }
        __syncthreads();
    }

    #pragma unroll
    for (int r = 0; r < 4; ++r) {
        float inv = 1.0f / l[r];
        size_t base = (size_t)(b * S + q0 + lq * 4 + r) * 256 + h * 32;
        Out[base + lm] = o0[r] * inv;
        Out[base + 16 + lm] = o1[r] * inv;
    }
}

extern "C" void kernel_launch(void* const* d_in, const int* in_sizes, int n_in,
                              void* d_out, int out_size, void* d_ws, size_t ws_size,
                              hipStream_t stream) {
    (void)in_sizes; (void)n_in; (void)out_size; (void)ws_size;
    const float* x    = (const float*)d_in[0];
    const float* ln1g = (const float*)d_in[1];
    const float* ln1b = (const float*)d_in[2];
    const float* Wq   = (const float*)d_in[3];
    const float* bq   = (const float*)d_in[4];
    const float* Wk   = (const float*)d_in[5];
    const float* bk   = (const float*)d_in[6];
    const float* Wv   = (const float*)d_in[7];
    const float* bv   = (const float*)d_in[8];
    const float* ln2g = (const float*)d_in[9];
    const float* ln2b = (const float*)d_in[10];
    const float* Wo1  = (const float*)d_in[11];
    const float* bo1  = (const float*)d_in[12];
    const float* Wo2  = (const float*)d_in[13];
    const float* bo2  = (const float*)d_in[14];
    const int*   mask = (const int*)d_in[15];
    float* out = (float*)d_out;

    const int S = SS, H = HH;
    const int T = BB * SS;                 // 8192 tokens
    const size_t NE = (size_t)T * DD;      // 2M elements
    float* ws    = (float*)d_ws;
    float* attn  = ws + 0 * NE;
    float* maskf = ws + 1 * NE;            // 8192 floats used
    unsigned short* q_bf   = (unsigned short*)(ws + 2 * NE);
    unsigned short* k_bf   = q_bf + NE;
    unsigned short* h_bf   = k_bf + NE;
    unsigned short* wt     = h_bf + NE;
    const int WC = 3 * DD * DD;            // 196608
    const int WM = DD * DD;
    unsigned short* wtq0 = wt;
    unsigned short* wtq1 = wt + WC;
    unsigned short* wtk0 = wt + 2 * WC;
    unsigned short* wtk1 = wt + 3 * WC;
    unsigned short* wtv0 = wt + 4 * WC;
    unsigned short* wtv1 = wt + 5 * WC;
    unsigned short* wto1 = wt + 6 * WC;
    unsigned short* wto2 = wt + 6 * WC + WM;
    unsigned short* vt_g = wt + 6 * WC + 2 * WM;  // transposed V [B*256][S]

    // fused: 8 weight transposes + LN1 + mask->float
    prep_kernel<<<1280 + T / 4 + 8, 256, 0, stream>>>(
        Wq, Wk, Wv, Wo1, Wo2, wt, x, ln1g, ln1b, h_bf, mask, maskf);

    // fused dual-layer temporal encoders (q/k/v); v writes Vt directly
    convdual_kernel<<<(T / 32) * 3, 256, 0, stream>>>(
        h_bf, wtq0, wtk0, wtv0, wtq1, wtk1, wtv1, bq, bk, bv,
        q_bf, k_bf, vt_g, S);

    // MFMA attention -> attn (fp32)
    attn_mfma_kernel<<<BB * H * (S / 64), 256, 0, stream>>>(q_bf, k_bf, vt_g, maskf, attn, S, H);

    // fused tail: LN2 + MLP1 + GELU + MLP2 + residual -> out
    tail_kernel<<<T / 16, 256, 0, stream>>>(
        x, attn, ln2g, ln2b, wto1, bo1, wto2, bo2, out, S);
}